// Round 1
// baseline (529.453 us; speedup 1.0000x reference)
//
#include <hip/hip_runtime.h>
#include <stdint.h>

// ---------------- problem constants ----------------
#define E_DIM 1024
#define M_DIM 256
#define B_DIM 4
#define S_DIM 2048
#define NTOK  8192      // B*S
#define CHUNK 64
#define NCHUNK 32       // S / CHUNK
#define NCB   128       // B * NCHUNK

typedef unsigned short u16;
typedef unsigned int   u32;
typedef __attribute__((ext_vector_type(8))) short short8;
typedef __attribute__((ext_vector_type(4))) float floatx4;

// ---------------- workspace layout (bytes) ----------------
#define OFF_WKQV   ((size_t)0)            // 768*1024 bf16 = 1,572,864
#define OFF_WOUT   ((size_t)1572864)      // 1024*256 bf16 = 524,288
#define OFF_WF1    ((size_t)2097152)      // 4096*1024 bf16 = 8,388,608
#define OFF_WF2    ((size_t)10485760)     // 8,388,608
#define OFF_BKQV   ((size_t)18874368)     // 768 f32
#define OFF_BETA   ((size_t)18877440)     // 8192 f32
#define OFF_DECAY  ((size_t)18910208)     // 8192 f32
#define OFF_P      ((size_t)18942976)     // 128*65 f32
#define OFF_WW     ((size_t)18976256)     // 128*64 f32
#define OFF_ABUF   ((size_t)19009024)     // 128*64*64 f32 = 2,097,152
#define OFF_XN     ((size_t)21106176)     // 8192*1024 bf16 = 16,777,216  [h, ffn2-partial alias]
#define OFF_KQV    ((size_t)37883392)     // 8192*768 f32 = 25,165,824    [kqv split-K partial A]
#define OFF_T      ((size_t)63049216)     // 128*65536 f32 = 33,554,432   [kqv partial B, then T, then y1]
#define OFF_STATES ((size_t)96603648)     // 128*65536 f32 = 33,554,432   [g starts here]
#define OFF_RO     ((size_t)130158080)    // 8192*256 bf16 = 4,194,304
#define OFF_H      OFF_XN                 // 8192*1024 bf16 (xn dead after kqv gemm)
#define OFF_Y1     OFF_T                  // 8192*1024 f32 (T dead after mem_scan)
#define OFF_G      OFF_STATES             // 8192*4096 bf16 = 67,108,864 (states+ro dead)
#define OFF_P2     OFF_XN                 // 8192*1024 f32 FFN2 split-K partial (h/kqv dead)

// ---------------- helpers ----------------
__device__ __forceinline__ u16 f2bf(float f) {
    union { float f; u32 u; } a; a.f = f;
    u32 u = a.u;
    return (u16)((u + 0x7fffu + ((u >> 16) & 1u)) >> 16);
}
__device__ __forceinline__ u32 pack2bf(float a, float b) {
    return (u32)f2bf(a) | ((u32)f2bf(b) << 16);
}
__device__ __forceinline__ float sigmoidf_(float x) { return 1.0f / (1.0f + expf(-x)); }

// async global->LDS, 16 bytes per lane; LDS dest contiguous in lane order.
__device__ __forceinline__ void gload_lds16(const u16* g, u16* l) {
    __builtin_amdgcn_global_load_lds((const __attribute__((address_space(1))) void*)g,
                                     (__attribute__((address_space(3))) void*)l, 16, 0, 0);
}

// XOR-swizzle (verified R4: SQ_LDS_BANK_CONFLICT -> 0)
__device__ __forceinline__ int sw_slot(int idx) {
    return ((idx & 3) ^ ((idx >> 3) & 3)) * 8;
}
__device__ __forceinline__ int sw_read(int row, int kc) {
    return row * 32 + ((kc ^ ((row >> 1) & 3)) << 3);
}

// two-value block reduction across 256 threads (4 waves)
__device__ __forceinline__ void block_reduce_2(float& a, float& b, float* red, int t) {
#pragma unroll
    for (int o = 32; o > 0; o >>= 1) { a += __shfl_xor(a, o); b += __shfl_xor(b, o); }
    if ((t & 63) == 0) { red[t >> 6] = a; red[4 + (t >> 6)] = b; }
    __syncthreads();
    a = red[0] + red[1] + red[2] + red[3];
    b = red[4] + red[5] + red[6] + red[7];
    __syncthreads();
}

// ---------------- unified weight conversion ----------------
__device__ __forceinline__ uint2 cvt4(float4 v) {
    uint2 o; o.x = pack2bf(v.x, v.y); o.y = pack2bf(v.z, v.w); return o;
}
__global__ void convert_weights(const float4* __restrict__ wk, const float4* __restrict__ wq,
                                const float4* __restrict__ wv, const float4* __restrict__ wo,
                                const float4* __restrict__ wf1in, const float4* __restrict__ wf2in,
                                const float* __restrict__ bk, const float* __restrict__ bq,
                                const float* __restrict__ bv,
                                uint2* __restrict__ wkqv, uint2* __restrict__ wout,
                                uint2* __restrict__ wf1, uint2* __restrict__ wf2,
                                float* __restrict__ bkqv) {
    int b = blockIdx.x, t = threadIdx.x;
    if (b < 768) {
        int i = b * 256 + t;
        int sec = i >> 16, off = i & 65535;
        const float4* s = (sec == 0) ? wk : ((sec == 1) ? wq : wv);
        wkqv[i] = cvt4(s[off]);
    } else if (b < 1024) {
        int i = (b - 768) * 256 + t;
        wout[i] = cvt4(wo[i]);
    } else if (b < 5120) {
        int i = (b - 1024) * 256 + t;
        wf1[i] = cvt4(wf1in[i]);
    } else if (b < 9216) {
        int i = (b - 5120) * 256 + t;
        wf2[i] = cvt4(wf2in[i]);
    } else {
        bkqv[t] = bk[t]; bkqv[256 + t] = bq[t]; bkqv[512 + t] = bv[t];
    }
}

// ---------------- LN kernels ----------------
__global__ __launch_bounds__(256) void ln1_gates(
    const float* __restrict__ x, const float* __restrict__ g, const float* __restrict__ b,
    const float* __restrict__ wgw, const float* __restrict__ bgw,
    const float* __restrict__ wgf, const float* __restrict__ bgf,
    u16* __restrict__ xn, float* __restrict__ beta, float* __restrict__ decay)
{
    __shared__ float red[8];
    const int row = blockIdx.x;
    const int t = threadIdx.x;
    const float4 v = ((const float4*)(x + (size_t)row * E_DIM))[t];
    float s  = v.x + v.y + v.z + v.w;
    float ss = v.x * v.x + v.y * v.y + v.z * v.z + v.w * v.w;
    block_reduce_2(s, ss, red, t);
    const float mean = s * (1.0f / E_DIM);
    const float var  = ss * (1.0f / E_DIM) - mean * mean;
    const float rstd = rsqrtf(var + 1e-5f);
    const float4 gg = ((const float4*)g)[t];
    const float4 bb = ((const float4*)b)[t];
    float4 xnv;
    xnv.x = (v.x - mean) * rstd * gg.x + bb.x;
    xnv.y = (v.y - mean) * rstd * gg.y + bb.y;
    xnv.z = (v.z - mean) * rstd * gg.z + bb.z;
    xnv.w = (v.w - mean) * rstd * gg.w + bb.w;
    uint2 o; o.x = pack2bf(xnv.x, xnv.y); o.y = pack2bf(xnv.z, xnv.w);
    ((uint2*)(xn + (size_t)row * E_DIM))[t] = o;
    const float4 w1 = ((const float4*)wgw)[t];
    const float4 w2 = ((const float4*)wgf)[t];
    float dg = xnv.x * w1.x + xnv.y * w1.y + xnv.z * w1.z + xnv.w * w1.w;
    float df = xnv.x * w2.x + xnv.y * w2.y + xnv.z * w2.z + xnv.w * w2.w;
    block_reduce_2(dg, df, red, t);
    if (t == 0) {
        beta[row]  = sigmoidf_(dg + bgw[0]);
        decay[row] = sigmoidf_(df + bgf[0]);
    }
}

__global__ __launch_bounds__(256) void ln2_kernel(
    const float* __restrict__ y1, const float* __restrict__ g, const float* __restrict__ b,
    u16* __restrict__ h)
{
    __shared__ float red[8];
    const int row = blockIdx.x;
    const int t = threadIdx.x;
    const float4 v = ((const float4*)(y1 + (size_t)row * E_DIM))[t];
    float s  = v.x + v.y + v.z + v.w;
    float ss = v.x * v.x + v.y * v.y + v.z * v.z + v.w * v.w;
    block_reduce_2(s, ss, red, t);
    const float mean = s * (1.0f / E_DIM);
    const float var  = ss * (1.0f / E_DIM) - mean * mean;
    const float rstd = rsqrtf(var + 1e-5f);
    const float4 gg = ((const float4*)g)[t];
    const float4 bb = ((const float4*)b)[t];
    float4 xnv;
    xnv.x = (v.x - mean) * rstd * gg.x + bb.x;
    xnv.y = (v.y - mean) * rstd * gg.y + bb.y;
    xnv.z = (v.z - mean) * rstd * gg.z + bb.z;
    xnv.w = (v.w - mean) * rstd * gg.w + bb.w;
    uint2 o; o.x = pack2bf(xnv.x, xnv.y); o.y = pack2bf(xnv.z, xnv.w);
    ((uint2*)(h + (size_t)row * E_DIM))[t] = o;
}

// ---------------- k/q/v: combine split-K partials + bias, then activations ----------------
__global__ __launch_bounds__(256) void kqv_act(float* __restrict__ pA,
                                               const float* __restrict__ pB,
                                               const float* __restrict__ bias) {
    __shared__ float red[8];
    const int row = blockIdx.x;
    const int t = threadIdx.x;
    float* p = pA + (size_t)row * 768;
    const float* q = pB + (size_t)row * 768;
    float kv = p[t]       + q[t]       + bias[t];
    float qv = p[256 + t] + q[256 + t] + bias[256 + t];
    float vv = p[512 + t] + q[512 + t] + bias[512 + t];
    float sk = kv * kv, sq = qv * qv;
    block_reduce_2(sk, sq, red, t);
    float nk = fmaxf(sqrtf(sk), 1e-12f);
    float nq = fmaxf(sqrtf(sq), 1e-12f);
    p[t]       = kv / nk;
    p[256 + t] = qv / nq;
    p[512 + t] = tanhf(vv);
}

// ---------------- chunk prep ----------------
__global__ void chunk_prep(const float* __restrict__ beta, const float* __restrict__ decay,
                           float* __restrict__ P, float* __restrict__ ww) {
    int cb = blockIdx.x;
    int b = cb >> 5, c = cb & 31;
    int tb = b * S_DIM + c * CHUNK;
    int j = threadIdx.x;
    __shared__ float d[64], bt[64], Ps[65];
    d[j]  = decay[tb + j];
    bt[j] = beta[tb + j];
    __syncthreads();
    if (j == 0) {
        float p = 1.0f; Ps[0] = 1.0f;
        for (int i = 0; i < 64; i++) { p *= d[i]; Ps[i + 1] = p; }
    }
    __syncthreads();
    P[cb * 65 + j] = Ps[j];
    if (j == 0) P[cb * 65 + 64] = Ps[64];
    ww[cb * 64 + j] = bt[j] / Ps[j + 1];
}

// ---------------- per-chunk state increment ----------------
__global__ __launch_bounds__(256) void t_kernel(const float* __restrict__ kqv,
                                                const float* __restrict__ P,
                                                const float* __restrict__ ww,
                                                float* __restrict__ T) {
    int cb = blockIdx.y;
    int tile = blockIdx.x;
    int r0 = (tile >> 2) * 64, c0 = (tile & 3) * 64;
    int b = cb >> 5, c = cb & 31;
    int tb = b * S_DIM + c * CHUNK;
    float p64 = P[cb * 65 + 64];
    __shared__ float Vs[64][65], Ks[64][65];
    int t = threadIdx.x;
#pragma unroll
    for (int i = 0; i < 16; i++) {
        int idx = t + i * 256; int j = idx >> 6, col = idx & 63;
        float sc = ww[cb * 64 + j] * p64;
        Vs[j][col] = kqv[(size_t)(tb + j) * 768 + 512 + r0 + col] * sc;
        Ks[j][col] = kqv[(size_t)(tb + j) * 768 + 0   + c0 + col];
    }
    __syncthreads();
    int tr = t >> 4, tc = t & 15;
    float a[4][4] = {};
    for (int j = 0; j < 64; j++) {
        float vv[4], kk[4];
#pragma unroll
        for (int r = 0; r < 4; r++)  vv[r] = Vs[j][tr * 4 + r];
#pragma unroll
        for (int cc = 0; cc < 4; cc++) kk[cc] = Ks[j][tc * 4 + cc];
#pragma unroll
        for (int r = 0; r < 4; r++)
#pragma unroll
            for (int cc = 0; cc < 4; cc++) a[r][cc] += vv[r] * kk[cc];
    }
#pragma unroll
    for (int r = 0; r < 4; r++)
#pragma unroll
        for (int cc = 0; cc < 4; cc++)
            T[(size_t)cb * 65536 + (size_t)(r0 + tr * 4 + r) * 256 + (c0 + tc * 4 + cc)] = a[r][cc];
}

// ---------------- element-parallel chunk scan ----------------
__global__ void mem_scan(const float* __restrict__ mem0, const float* __restrict__ T,
                         const float* __restrict__ P, float* __restrict__ states,
                         float* __restrict__ memOut) {
    int gid = blockIdx.x * 256 + threadIdx.x;
    int b = gid >> 16; int e = gid & 65535;
    float s = mem0[gid];
    for (int c = 0; c < NCHUNK; c++) {
        int cb = b * NCHUNK + c;
        states[(size_t)cb * 65536 + e] = s;
        s = P[cb * 65 + 64] * s + T[(size_t)cb * 65536 + e];
    }
    memOut[gid] = s;
}

// ---------------- intra-chunk attention matrix ----------------
__global__ __launch_bounds__(256) void qk_attn(const float* __restrict__ kqv,
                                               const float* __restrict__ P,
                                               const float* __restrict__ ww,
                                               float* __restrict__ Abuf) {
    int cb = blockIdx.x;
    int b = cb >> 5, c = cb & 31;
    int tb = b * S_DIM + c * CHUNK;
    __shared__ float Qs[64][65], Ks[64][65];
    int t = threadIdx.x;
    int tr = t >> 4, tc = t & 15;
    float acc[4][4] = {};
    for (int kt = 0; kt < 4; kt++) {
        __syncthreads();
#pragma unroll
        for (int i = 0; i < 16; i++) {
            int idx = t + i * 256; int rr = idx >> 6, cc2 = idx & 63;
            Qs[rr][cc2] = kqv[(size_t)(tb + rr) * 768 + 256 + kt * 64 + cc2];
            Ks[rr][cc2] = kqv[(size_t)(tb + rr) * 768 + 0   + kt * 64 + cc2];
        }
        __syncthreads();
        for (int kk = 0; kk < 64; kk++) {
            float qq[4], kx[4];
#pragma unroll
            for (int r = 0; r < 4; r++)  qq[r] = Qs[tr * 4 + r][kk];
#pragma unroll
            for (int cc = 0; cc < 4; cc++) kx[cc] = Ks[tc * 4 + cc][kk];
#pragma unroll
            for (int r = 0; r < 4; r++)
#pragma unroll
                for (int cc = 0; cc < 4; cc++) acc[r][cc] += qq[r] * kx[cc];
        }
    }
#pragma unroll
    for (int r = 0; r < 4; r++) {
#pragma unroll
        for (int cc = 0; cc < 4; cc++) {
            int i = tr * 4 + r, j = tc * 4 + cc;
            float v = (j < i) ? acc[r][cc] * (P[cb * 65 + i] * ww[cb * 64 + j]) : 0.0f;
            Abuf[(size_t)cb * 4096 + i * 64 + j] = v;
        }
    }
}

// ---------------- readout ----------------
__global__ __launch_bounds__(256) void readout_k(const float* __restrict__ kqv,
                                                 const float* __restrict__ Abuf,
                                                 const float* __restrict__ states,
                                                 const float* __restrict__ P,
                                                 u16* __restrict__ ro) {
    int cb = blockIdx.y;
    int rt = blockIdx.x;
    int b = cb >> 5, c = cb & 31;
    int tb = b * S_DIM + c * CHUNK;
    int r0 = rt * 64;
    __shared__ float As[64][65], Vs[64][65], Qs[64][65], Ms[64][65];
    int t = threadIdx.x;
    int tr = t >> 4, tc = t & 15;
#pragma unroll
    for (int i = 0; i < 16; i++) {
        int idx = t + i * 256; int rr = idx >> 6, cc2 = idx & 63;
        As[rr][cc2] = Abuf[(size_t)cb * 4096 + rr * 64 + cc2];
        Vs[rr][cc2] = kqv[(size_t)(tb + rr) * 768 + 512 + r0 + cc2];
    }
    __syncthreads();
    float acc[4][4] = {};
    for (int j = 0; j < 64; j++) {
        float aa[4], vv[4];
#pragma unroll
        for (int r = 0; r < 4; r++)  aa[r] = As[tr * 4 + r][j];
#pragma unroll
        for (int cc = 0; cc < 4; cc++) vv[cc] = Vs[j][tc * 4 + cc];
#pragma unroll
        for (int r = 0; r < 4; r++)
#pragma unroll
            for (int cc = 0; cc < 4; cc++) acc[r][cc] += aa[r] * vv[cc];
    }
    float acc2[4][4] = {};
    for (int kt = 0; kt < 4; kt++) {
        __syncthreads();
#pragma unroll
        for (int i = 0; i < 16; i++) {
            int idx = t + i * 256; int rr = idx >> 6, cc2 = idx & 63;
            Qs[rr][cc2] = kqv[(size_t)(tb + rr) * 768 + 256 + kt * 64 + cc2];
            Ms[rr][cc2] = states[(size_t)cb * 65536 + (size_t)(r0 + rr) * 256 + kt * 64 + cc2];
        }
        __syncthreads();
        for (int kk = 0; kk < 64; kk++) {
            float qq[4], mm[4];
#pragma unroll
            for (int r = 0; r < 4; r++)  qq[r] = Qs[tr * 4 + r][kk];
#pragma unroll
            for (int cc = 0; cc < 4; cc++) mm[cc] = Ms[tc * 4 + cc][kk];
#pragma unroll
            for (int r = 0; r < 4; r++)
#pragma unroll
                for (int cc = 0; cc < 4; cc++) acc2[r][cc] += qq[r] * mm[cc];
        }
    }
#pragma unroll
    for (int r = 0; r < 4; r++) {
#pragma unroll
        for (int cc = 0; cc < 4; cc++) {
            int i = tr * 4 + r;
            float val = acc[r][cc] + P[cb * 65 + i] * acc2[r][cc];
            ro[(size_t)(tb + i) * 256 + r0 + tc * 4 + cc] = f2bf(val);
        }
    }
}

// ---------------- split-K combine: out += partial ----------------
__global__ __launch_bounds__(256) void combine_k(float4* __restrict__ out,
                                                 const float4* __restrict__ part) {
    int i = blockIdx.x * 256 + threadIdx.x;
    float4 a = out[i], b = part[i];
    a.x += b.x; a.y += b.y; a.z += b.z; a.w += b.w;
    out[i] = a;
}

// ---------------- bf16 MFMA GEMM: C[M,N] = A[M,K] @ B[N,K]^T (+epilogue) ----------------
// BMx128 tile, BK=32, 256 threads, 16x16x32 MFMA. XOR-swizzled LDS (0 conflicts, R4).
// R6: TRIPLE-buffered LDS + counted vmcnt + raw s_barrier. The old 2-buf version's
// __syncthreads() forced "s_waitcnt vmcnt(0)" every K-iter -> full global-load
// round-trip stall that no wave can hide (MfmaUtil 19%). Now tile t+2 is staged
// while tile t computes; at end of iter t we wait vmcnt(LPI) -> tile t+1's loads
// (issued at iter t-1) are landed, tile t+2's stay in flight ACROSS the barrier.
// Proof of safety: tile t+2's buffer was last read at iter t-1; those ds_reads
// complete (lgkmcnt before MFMA) before iter t-1's end barrier, and the stage
// issues sit after it in program order. LPI = loads/iter = 4 (BM=128) or 3 (BM=64).
// XCD-aware tile swizzle (MY>0) unchanged (R5).
#define EPI_BIAS   0
#define EPI_RESID  1
#define EPI_GELU   2
#define EPI_SPART  3
#define EPI_SRESID 4

template<int EPI, int BM, int MY, int SQH, int SQW>
__global__ __launch_bounds__(256) void gemm_bt(
    const u16* __restrict__ A, int lda,
    const u16* __restrict__ B, int ldb,
    const float* __restrict__ bias,
    const float* __restrict__ resid,
    float* __restrict__ outF, u16* __restrict__ outB,
    int ldc, int K, float* __restrict__ part)
{
    constexpr int MI = BM / 32;
    __shared__ u16 As[3][BM * 32];
    __shared__ u16 Bs[3][128 * 32];
    const int t = threadIdx.x;
    const int lane = t & 63;
    const int w = t >> 6;
    const int waveM = (w >> 1) * (BM / 2);
    const int waveN = (w & 1) * 64;

    int bx, by;
    if (MY == 0) {
        bx = blockIdx.x; by = blockIdx.y;
    } else {
        const u32 NX = gridDim.x;
        u32 flat = blockIdx.x + NX * blockIdx.y;
        u32 xcd = flat & 7;
        u32 local = flat >> 3;                 // [0, MY*NX)
        u32 perBand = (u32)SQH * NX;
        u32 band = local / perBand;
        u32 rem  = local - band * perBand;
        u32 sq   = rem / (SQH * SQW);
        u32 wloc = rem - sq * (SQH * SQW);
        u32 wy = wloc / SQW, wx = wloc - wy * SQW;
        by = xcd * MY + band * SQH + wy;
        bx = sq * SQW + wx;
    }

    const int m0 = by * BM;
    const int n0 = bx * 128;
    const size_t koff = (size_t)blockIdx.z * K;

    const int sr = t >> 2, scw = sw_slot(t);
    const u16* Ag0 = A + (size_t)(m0 + sr) * lda + koff + scw;
    const u16* Ag1 = A + (size_t)(m0 + 64 + sr) * lda + koff + scw;   // BM==128 only
    const u16* Bg0 = B + (size_t)(n0 + sr) * ldb + koff + scw;
    const u16* Bg1 = B + (size_t)(n0 + 64 + sr) * ldb + koff + scw;

    floatx4 acc[MI][4] = {};

    const int kc = lane >> 4;
    const int rsel = lane & 15;
    const int NK = K >> 5;

    // prologue: stage tiles 0 and 1 (2*LPI issues), wait for tile 0 only.
    gload_lds16(Ag0, As[0] + t * 8);
    if (BM == 128) gload_lds16(Ag1, As[0] + (t + 256) * 8);
    gload_lds16(Bg0, Bs[0] + t * 8);
    gload_lds16(Bg1, Bs[0] + (t + 256) * 8);
    gload_lds16(Ag0 + 32, As[1] + t * 8);
    if (BM == 128) gload_lds16(Ag1 + 32, As[1] + (t + 256) * 8);
    gload_lds16(Bg0 + 32, Bs[1] + t * 8);
    gload_lds16(Bg1 + 32, Bs[1] + (t + 256) * 8);
    if constexpr (BM == 128) { asm volatile("s_waitcnt vmcnt(4)" ::: "memory"); }
    else                     { asm volatile("s_waitcnt vmcnt(3)" ::: "memory"); }
    __builtin_amdgcn_s_barrier();
    __builtin_amdgcn_sched_barrier(0);

    int cur = 0, nx1 = 1, nx2 = 2;
    for (int kt = 0; kt < NK; kt++) {
        // stage tile kt+2 into the buffer freed at iter kt-1
        if (kt + 2 < NK) {
            const int kof = (kt + 2) * 32;
            u16* Ad = As[nx2];
            u16* Bd = Bs[nx2];
            gload_lds16(Ag0 + kof, Ad + t * 8);
            if (BM == 128) gload_lds16(Ag1 + kof, Ad + (t + 256) * 8);
            gload_lds16(Bg0 + kof, Bd + t * 8);
            gload_lds16(Bg1 + kof, Bd + (t + 256) * 8);
        }
        const u16* Ac = As[cur];
        const u16* Bc = Bs[cur];
        short8 af[MI], bfr[4];
#pragma unroll
        for (int i = 0; i < MI; i++)
            af[i] = *(const short8*)(Ac + sw_read(waveM + i * 16 + rsel, kc));
#pragma unroll
        for (int j = 0; j < 4; j++)
            bfr[j] = *(const short8*)(Bc + sw_read(waveN + j * 16 + rsel, kc));
#pragma unroll
        for (int i = 0; i < MI; i++)
#pragma unroll
            for (int j = 0; j < 4; j++)
                acc[i][j] = __builtin_amdgcn_mfma_f32_16x16x32_bf16(af[i], bfr[j], acc[i][j], 0, 0, 0);
        // counted wait: tile kt+1 landed, tile kt+2 stays in flight (never drain to 0 mid-loop)
        if (kt + 2 < NK) {
            if constexpr (BM == 128) { asm volatile("s_waitcnt vmcnt(4)" ::: "memory"); }
            else                     { asm volatile("s_waitcnt vmcnt(3)" ::: "memory"); }
        } else {
            asm volatile("s_waitcnt vmcnt(0)" ::: "memory");
        }
        __builtin_amdgcn_s_barrier();
        __builtin_amdgcn_sched_barrier(0);
        const int tmp = cur; cur = nx1; nx1 = nx2; nx2 = tmp;
    }

    const bool zmain = (blockIdx.z == 0);
    const int rbase = (lane >> 4) * 4;
#pragma unroll
    for (int i = 0; i < MI; i++) {
#pragma unroll
        for (int j = 0; j < 4; j++) {
            const int col = n0 + waveN + j * 16 + rsel;
            float bv = 0.0f;
            if (EPI == EPI_BIAS || EPI == EPI_RESID || EPI == EPI_GELU) bv = bias[col];
            if (EPI == EPI_SRESID && zmain) bv = bias[col];
#pragma unroll
            for (int r = 0; r < 4; r++) {
                const int row = m0 + waveM + i * 16 + rbase + r;
                const size_t oidx = (size_t)row * ldc + col;
                float v = acc[i][j][r] + bv;
                if (EPI == EPI_BIAS) {
                    outF[oidx] = v;
                } else if (EPI == EPI_RESID) {
                    outF[oidx] = v + resid[oidx];
                } else if (EPI == EPI_GELU) {
                    float gl = 0.5f * v * (1.0f + erff(v * 0.70710678118654752f));
                    outB[oidx] = f2bf(gl);
                } else if (EPI == EPI_SPART) {
                    (zmain ? outF : part)[oidx] = v;
                } else { // EPI_SRESID
                    if (zmain) outF[oidx] = v + resid[oidx];
                    else       part[oidx] = v;
                }
            }
        }
    }
}

// ---------------- launch ----------------
extern "C" void kernel_launch(void* const* d_in, const int* in_sizes, int n_in,
                              void* d_out, int out_size, void* d_ws, size_t ws_size,
                              hipStream_t stream) {
    const float* x     = (const float*)d_in[0];
    const float* mem0  = (const float*)d_in[1];
    const float* w_k   = (const float*)d_in[2];
    const float* b_k   = (const float*)d_in[3];
    const float* w_q   = (const float*)d_in[4];
    const float* b_q   = (const float*)d_in[5];
    const float* w_v   = (const float*)d_in[6];
    const float* b_v   = (const float*)d_in[7];
    const float* w_out = (const float*)d_in[8];
    const float* b_out = (const float*)d_in[9];
    const float* w_gw  = (const float*)d_in[10];
    const float* b_gw  = (const float*)d_in[11];
    const float* w_gf  = (const float*)d_in[12];
    const float* b_gf  = (const float*)d_in[13];
    const float* ln1g  = (const float*)d_in[14];
    const float* ln1b  = (const float*)d_in[15];
    const float* ln2g  = (const float*)d_in[16];
    const float* ln2b  = (const float*)d_in[17];
    const float* w_f1  = (const float*)d_in[18];
    const float* b_f1  = (const float*)d_in[19];
    const float* w_f2  = (const float*)d_in[20];
    const float* b_f2  = (const float*)d_in[21];

    char* ws = (char*)d_ws;
    u16*   wkqv  = (u16*)(ws + OFF_WKQV);
    u16*   wout  = (u16*)(ws + OFF_WOUT);
    u16*   wf1   = (u16*)(ws + OFF_WF1);
    u16*   wf2   = (u16*)(ws + OFF_WF2);
    float* bkqv  = (float*)(ws + OFF_BKQV);
    float* beta  = (float*)(ws + OFF_BETA);
    float* decay = (float*)(ws + OFF_DECAY);
    float* P     = (float*)(ws + OFF_P);
    float* ww    = (float*)(ws + OFF_WW);
    float* Abuf  = (float*)(ws + OFF_ABUF);
    u16*   xn    = (u16*)(ws + OFF_XN);
    float* kqv   = (float*)(ws + OFF_KQV);
    float* kqvPB = (float*)(ws + OFF_T);
    float* T     = (float*)(ws + OFF_T);
    float* states= (float*)(ws + OFF_STATES);
    u16*   ro    = (u16*)(ws + OFF_RO);
    u16*   h     = (u16*)(ws + OFF_H);
    float* y1    = (float*)(ws + OFF_Y1);
    u16*   g     = (u16*)(ws + OFF_G);
    float* p2    = (float*)(ws + OFF_P2);

    float* out_x   = (float*)d_out;
    float* out_mem = out_x + (size_t)NTOK * E_DIM;

    convert_weights<<<9217, 256, 0, stream>>>(
        (const float4*)w_k, (const float4*)w_q, (const float4*)w_v,
        (const float4*)w_out, (const float4*)w_f1, (const float4*)w_f2,
        b_k, b_q, b_v,
        (uint2*)wkqv, (uint2*)wout, (uint2*)wf1, (uint2*)wf2, bkqv);

    ln1_gates<<<NTOK, 256, 0, stream>>>(x, ln1g, ln1b, w_gw, b_gw, w_gf, b_gf, xn, beta, decay);

    // k/q/v: split-K(2) full density (B fits L2 -> no tile swizzle needed)
    gemm_bt<EPI_SPART, 128, 0, 0, 0><<<dim3(6, 64, 2), 256, 0, stream>>>(
        xn, 1024, wkqv, 1024, nullptr, nullptr, kqv, nullptr, 768, 512, kqvPB);
    kqv_act<<<NTOK, 256, 0, stream>>>(kqv, kqvPB, bkqv);

    chunk_prep<<<NCB, 64, 0, stream>>>(beta, decay, P, ww);
    t_kernel<<<dim3(16, NCB), 256, 0, stream>>>(kqv, P, ww, T);
    mem_scan<<<1024, 256, 0, stream>>>(mem0, T, P, states, out_mem);
    qk_attn<<<NCB, 256, 0, stream>>>(kqv, P, ww, Abuf);
    readout_k<<<dim3(4, NCB), 256, 0, stream>>>(kqv, Abuf, states, P, ro);

    gemm_bt<EPI_RESID, 64, 0, 0, 0><<<dim3(8, 128), 256, 0, stream>>>(
        ro, 256, wout, 256, b_out, x, y1, nullptr, 1024, 256, nullptr);

    ln2_kernel<<<NTOK, 256, 0, stream>>>(y1, ln2g, ln2b, h);
    // FFN1: XCD swizzle, band MY=8 m-tiles/XCD, 8x8 sub-squares (2MB A + 2MB B in L2)
    gemm_bt<EPI_GELU, 128, 8, 8, 8><<<dim3(32, 64), 256, 0, stream>>>(
        h, 1024, wf1, 1024, b_f1, nullptr, nullptr, g, 4096, 1024, nullptr);
    // FFN2: split-K(2) + XCD swizzle, 4x4 sub-squares (K=2048 -> 512KB tiles)
    gemm_bt<EPI_SRESID, 128, 8, 4, 4><<<dim3(8, 64, 2), 256, 0, stream>>>(
        g, 4096, wf2, 4096, b_f2, y1, out_x, nullptr, 1024, 2048, p2);
    combine_k<<<8192, 256, 0, stream>>>((float4*)out_x, (const float4*)p2);
}

// Round 2
// 524.035 us; speedup vs baseline: 1.0103x; 1.0103x over previous
//
#include <hip/hip_runtime.h>
#include <stdint.h>

// ---------------- problem constants ----------------
#define E_DIM 1024
#define M_DIM 256
#define B_DIM 4
#define S_DIM 2048
#define NTOK  8192      // B*S
#define CHUNK 64
#define NCHUNK 32       // S / CHUNK
#define NCB   128       // B * NCHUNK

typedef unsigned short u16;
typedef unsigned int   u32;
typedef __attribute__((ext_vector_type(8))) short short8;
typedef __attribute__((ext_vector_type(4))) float floatx4;

// ---------------- workspace layout (bytes) ----------------
#define OFF_WKQV   ((size_t)0)            // 768*1024 bf16 = 1,572,864
#define OFF_WOUT   ((size_t)1572864)      // 1024*256 bf16 = 524,288
#define OFF_WF1    ((size_t)2097152)      // 4096*1024 bf16 = 8,388,608
#define OFF_WF2    ((size_t)10485760)     // 8,388,608
#define OFF_BKQV   ((size_t)18874368)     // 768 f32
#define OFF_BETA   ((size_t)18877440)     // 8192 f32
#define OFF_DECAY  ((size_t)18910208)     // 8192 f32
#define OFF_P      ((size_t)18942976)     // 128*65 f32
#define OFF_WW     ((size_t)18976256)     // 128*64 f32
#define OFF_ABUF   ((size_t)19009024)     // 128*64*64 f32 = 2,097,152
#define OFF_XN     ((size_t)21106176)     // 8192*1024 bf16 = 16,777,216  [h, ffn2-partial alias]
#define OFF_KQV    ((size_t)37883392)     // 8192*768 f32 = 25,165,824    [kqv split-K partial A]
#define OFF_T      ((size_t)63049216)     // 128*65536 f32 = 33,554,432   [kqv partial B, then T, then y1]
#define OFF_STATES ((size_t)96603648)     // 128*65536 f32 = 33,554,432   [g starts here]
#define OFF_RO     ((size_t)130158080)    // 8192*256 bf16 = 4,194,304
#define OFF_H      OFF_XN                 // 8192*1024 bf16 (xn dead after kqv gemm)
#define OFF_Y1     OFF_T                  // 8192*1024 f32 (T dead after mem_scan)
#define OFF_G      OFF_STATES             // 8192*4096 bf16 = 67,108,864 (states+ro dead)
#define OFF_P2     OFF_XN                 // 8192*1024 f32 FFN2 split-K partial (h/kqv dead)

// ---------------- helpers ----------------
__device__ __forceinline__ u16 f2bf(float f) {
    union { float f; u32 u; } a; a.f = f;
    u32 u = a.u;
    return (u16)((u + 0x7fffu + ((u >> 16) & 1u)) >> 16);
}
__device__ __forceinline__ u32 pack2bf(float a, float b) {
    return (u32)f2bf(a) | ((u32)f2bf(b) << 16);
}
__device__ __forceinline__ float sigmoidf_(float x) { return 1.0f / (1.0f + expf(-x)); }

// async global->LDS, 16 bytes per lane; LDS dest contiguous in lane order.
__device__ __forceinline__ void gload_lds16(const u16* g, u16* l) {
    __builtin_amdgcn_global_load_lds((const __attribute__((address_space(1))) void*)g,
                                     (__attribute__((address_space(3))) void*)l, 16, 0, 0);
}

// XOR-swizzle for a [rows][32] u16 region (verified: SQ_LDS_BANK_CONFLICT -> 0)
__device__ __forceinline__ int sw_slot(int idx) {
    return ((idx & 3) ^ ((idx >> 3) & 3)) * 8;
}
__device__ __forceinline__ int sw_read(int row, int kc) {
    return row * 32 + ((kc ^ ((row >> 1) & 3)) << 3);
}

// two-value block reduction across 256 threads (4 waves)
__device__ __forceinline__ void block_reduce_2(float& a, float& b, float* red, int t) {
#pragma unroll
    for (int o = 32; o > 0; o >>= 1) { a += __shfl_xor(a, o); b += __shfl_xor(b, o); }
    if ((t & 63) == 0) { red[t >> 6] = a; red[4 + (t >> 6)] = b; }
    __syncthreads();
    a = red[0] + red[1] + red[2] + red[3];
    b = red[4] + red[5] + red[6] + red[7];
    __syncthreads();
}

// ---------------- unified weight conversion ----------------
__device__ __forceinline__ uint2 cvt4(float4 v) {
    uint2 o; o.x = pack2bf(v.x, v.y); o.y = pack2bf(v.z, v.w); return o;
}
__global__ void convert_weights(const float4* __restrict__ wk, const float4* __restrict__ wq,
                                const float4* __restrict__ wv, const float4* __restrict__ wo,
                                const float4* __restrict__ wf1in, const float4* __restrict__ wf2in,
                                const float* __restrict__ bk, const float* __restrict__ bq,
                                const float* __restrict__ bv,
                                uint2* __restrict__ wkqv, uint2* __restrict__ wout,
                                uint2* __restrict__ wf1, uint2* __restrict__ wf2,
                                float* __restrict__ bkqv) {
    int b = blockIdx.x, t = threadIdx.x;
    if (b < 768) {
        int i = b * 256 + t;
        int sec = i >> 16, off = i & 65535;
        const float4* s = (sec == 0) ? wk : ((sec == 1) ? wq : wv);
        wkqv[i] = cvt4(s[off]);
    } else if (b < 1024) {
        int i = (b - 768) * 256 + t;
        wout[i] = cvt4(wo[i]);
    } else if (b < 5120) {
        int i = (b - 1024) * 256 + t;
        wf1[i] = cvt4(wf1in[i]);
    } else if (b < 9216) {
        int i = (b - 5120) * 256 + t;
        wf2[i] = cvt4(wf2in[i]);
    } else {
        bkqv[t] = bk[t]; bkqv[256 + t] = bq[t]; bkqv[512 + t] = bv[t];
    }
}

// ---------------- LN kernels ----------------
__global__ __launch_bounds__(256) void ln1_gates(
    const float* __restrict__ x, const float* __restrict__ g, const float* __restrict__ b,
    const float* __restrict__ wgw, const float* __restrict__ bgw,
    const float* __restrict__ wgf, const float* __restrict__ bgf,
    u16* __restrict__ xn, float* __restrict__ beta, float* __restrict__ decay)
{
    __shared__ float red[8];
    const int row = blockIdx.x;
    const int t = threadIdx.x;
    const float4 v = ((const float4*)(x + (size_t)row * E_DIM))[t];
    float s  = v.x + v.y + v.z + v.w;
    float ss = v.x * v.x + v.y * v.y + v.z * v.z + v.w * v.w;
    block_reduce_2(s, ss, red, t);
    const float mean = s * (1.0f / E_DIM);
    const float var  = ss * (1.0f / E_DIM) - mean * mean;
    const float rstd = rsqrtf(var + 1e-5f);
    const float4 gg = ((const float4*)g)[t];
    const float4 bb = ((const float4*)b)[t];
    float4 xnv;
    xnv.x = (v.x - mean) * rstd * gg.x + bb.x;
    xnv.y = (v.y - mean) * rstd * gg.y + bb.y;
    xnv.z = (v.z - mean) * rstd * gg.z + bb.z;
    xnv.w = (v.w - mean) * rstd * gg.w + bb.w;
    uint2 o; o.x = pack2bf(xnv.x, xnv.y); o.y = pack2bf(xnv.z, xnv.w);
    ((uint2*)(xn + (size_t)row * E_DIM))[t] = o;
    const float4 w1 = ((const float4*)wgw)[t];
    const float4 w2 = ((const float4*)wgf)[t];
    float dg = xnv.x * w1.x + xnv.y * w1.y + xnv.z * w1.z + xnv.w * w1.w;
    float df = xnv.x * w2.x + xnv.y * w2.y + xnv.z * w2.z + xnv.w * w2.w;
    block_reduce_2(dg, df, red, t);
    if (t == 0) {
        beta[row]  = sigmoidf_(dg + bgw[0]);
        decay[row] = sigmoidf_(df + bgf[0]);
    }
}

__global__ __launch_bounds__(256) void ln2_kernel(
    const float* __restrict__ y1, const float* __restrict__ g, const float* __restrict__ b,
    u16* __restrict__ h)
{
    __shared__ float red[8];
    const int row = blockIdx.x;
    const int t = threadIdx.x;
    const float4 v = ((const float4*)(y1 + (size_t)row * E_DIM))[t];
    float s  = v.x + v.y + v.z + v.w;
    float ss = v.x * v.x + v.y * v.y + v.z * v.z + v.w * v.w;
    block_reduce_2(s, ss, red, t);
    const float mean = s * (1.0f / E_DIM);
    const float var  = ss * (1.0f / E_DIM) - mean * mean;
    const float rstd = rsqrtf(var + 1e-5f);
    const float4 gg = ((const float4*)g)[t];
    const float4 bb = ((const float4*)b)[t];
    float4 xnv;
    xnv.x = (v.x - mean) * rstd * gg.x + bb.x;
    xnv.y = (v.y - mean) * rstd * gg.y + bb.y;
    xnv.z = (v.z - mean) * rstd * gg.z + bb.z;
    xnv.w = (v.w - mean) * rstd * gg.w + bb.w;
    uint2 o; o.x = pack2bf(xnv.x, xnv.y); o.y = pack2bf(xnv.z, xnv.w);
    ((uint2*)(h + (size_t)row * E_DIM))[t] = o;
}

// ---------------- k/q/v: combine split-K partials + bias, then activations ----------------
__global__ __launch_bounds__(256) void kqv_act(float* __restrict__ pA,
                                               const float* __restrict__ pB,
                                               const float* __restrict__ bias) {
    __shared__ float red[8];
    const int row = blockIdx.x;
    const int t = threadIdx.x;
    float* p = pA + (size_t)row * 768;
    const float* q = pB + (size_t)row * 768;
    float kv = p[t]       + q[t]       + bias[t];
    float qv = p[256 + t] + q[256 + t] + bias[256 + t];
    float vv = p[512 + t] + q[512 + t] + bias[512 + t];
    float sk = kv * kv, sq = qv * qv;
    block_reduce_2(sk, sq, red, t);
    float nk = fmaxf(sqrtf(sk), 1e-12f);
    float nq = fmaxf(sqrtf(sq), 1e-12f);
    p[t]       = kv / nk;
    p[256 + t] = qv / nq;
    p[512 + t] = tanhf(vv);
}

// ---------------- chunk prep ----------------
__global__ void chunk_prep(const float* __restrict__ beta, const float* __restrict__ decay,
                           float* __restrict__ P, float* __restrict__ ww) {
    int cb = blockIdx.x;
    int b = cb >> 5, c = cb & 31;
    int tb = b * S_DIM + c * CHUNK;
    int j = threadIdx.x;
    __shared__ float d[64], bt[64], Ps[65];
    d[j]  = decay[tb + j];
    bt[j] = beta[tb + j];
    __syncthreads();
    if (j == 0) {
        float p = 1.0f; Ps[0] = 1.0f;
        for (int i = 0; i < 64; i++) { p *= d[i]; Ps[i + 1] = p; }
    }
    __syncthreads();
    P[cb * 65 + j] = Ps[j];
    if (j == 0) P[cb * 65 + 64] = Ps[64];
    ww[cb * 64 + j] = bt[j] / Ps[j + 1];
}

// ---------------- per-chunk state increment ----------------
__global__ __launch_bounds__(256) void t_kernel(const float* __restrict__ kqv,
                                                const float* __restrict__ P,
                                                const float* __restrict__ ww,
                                                float* __restrict__ T) {
    int cb = blockIdx.y;
    int tile = blockIdx.x;
    int r0 = (tile >> 2) * 64, c0 = (tile & 3) * 64;
    int b = cb >> 5, c = cb & 31;
    int tb = b * S_DIM + c * CHUNK;
    float p64 = P[cb * 65 + 64];
    __shared__ float Vs[64][65], Ks[64][65];
    int t = threadIdx.x;
#pragma unroll
    for (int i = 0; i < 16; i++) {
        int idx = t + i * 256; int j = idx >> 6, col = idx & 63;
        float sc = ww[cb * 64 + j] * p64;
        Vs[j][col] = kqv[(size_t)(tb + j) * 768 + 512 + r0 + col] * sc;
        Ks[j][col] = kqv[(size_t)(tb + j) * 768 + 0   + c0 + col];
    }
    __syncthreads();
    int tr = t >> 4, tc = t & 15;
    float a[4][4] = {};
    for (int j = 0; j < 64; j++) {
        float vv[4], kk[4];
#pragma unroll
        for (int r = 0; r < 4; r++)  vv[r] = Vs[j][tr * 4 + r];
#pragma unroll
        for (int cc = 0; cc < 4; cc++) kk[cc] = Ks[j][tc * 4 + cc];
#pragma unroll
        for (int r = 0; r < 4; r++)
#pragma unroll
            for (int cc = 0; cc < 4; cc++) a[r][cc] += vv[r] * kk[cc];
    }
#pragma unroll
    for (int r = 0; r < 4; r++)
#pragma unroll
        for (int cc = 0; cc < 4; cc++)
            T[(size_t)cb * 65536 + (size_t)(r0 + tr * 4 + r) * 256 + (c0 + tc * 4 + cc)] = a[r][cc];
}

// ---------------- element-parallel chunk scan ----------------
__global__ void mem_scan(const float* __restrict__ mem0, const float* __restrict__ T,
                         const float* __restrict__ P, float* __restrict__ states,
                         float* __restrict__ memOut) {
    int gid = blockIdx.x * 256 + threadIdx.x;
    int b = gid >> 16; int e = gid & 65535;
    float s = mem0[gid];
    for (int c = 0; c < NCHUNK; c++) {
        int cb = b * NCHUNK + c;
        states[(size_t)cb * 65536 + e] = s;
        s = P[cb * 65 + 64] * s + T[(size_t)cb * 65536 + e];
    }
    memOut[gid] = s;
}

// ---------------- intra-chunk attention matrix ----------------
__global__ __launch_bounds__(256) void qk_attn(const float* __restrict__ kqv,
                                               const float* __restrict__ P,
                                               const float* __restrict__ ww,
                                               float* __restrict__ Abuf) {
    int cb = blockIdx.x;
    int b = cb >> 5, c = cb & 31;
    int tb = b * S_DIM + c * CHUNK;
    __shared__ float Qs[64][65], Ks[64][65];
    int t = threadIdx.x;
    int tr = t >> 4, tc = t & 15;
    float acc[4][4] = {};
    for (int kt = 0; kt < 4; kt++) {
        __syncthreads();
#pragma unroll
        for (int i = 0; i < 16; i++) {
            int idx = t + i * 256; int rr = idx >> 6, cc2 = idx & 63;
            Qs[rr][cc2] = kqv[(size_t)(tb + rr) * 768 + 256 + kt * 64 + cc2];
            Ks[rr][cc2] = kqv[(size_t)(tb + rr) * 768 + 0   + kt * 64 + cc2];
        }
        __syncthreads();
        for (int kk = 0; kk < 64; kk++) {
            float qq[4], kx[4];
#pragma unroll
            for (int r = 0; r < 4; r++)  qq[r] = Qs[tr * 4 + r][kk];
#pragma unroll
            for (int cc = 0; cc < 4; cc++) kx[cc] = Ks[tc * 4 + cc][kk];
#pragma unroll
            for (int r = 0; r < 4; r++)
#pragma unroll
                for (int cc = 0; cc < 4; cc++) acc[r][cc] += qq[r] * kx[cc];
        }
    }
#pragma unroll
    for (int r = 0; r < 4; r++) {
#pragma unroll
        for (int cc = 0; cc < 4; cc++) {
            int i = tr * 4 + r, j = tc * 4 + cc;
            float v = (j < i) ? acc[r][cc] * (P[cb * 65 + i] * ww[cb * 64 + j]) : 0.0f;
            Abuf[(size_t)cb * 4096 + i * 64 + j] = v;
        }
    }
}

// ---------------- readout ----------------
__global__ __launch_bounds__(256) void readout_k(const float* __restrict__ kqv,
                                                 const float* __restrict__ Abuf,
                                                 const float* __restrict__ states,
                                                 const float* __restrict__ P,
                                                 u16* __restrict__ ro) {
    int cb = blockIdx.y;
    int rt = blockIdx.x;
    int b = cb >> 5, c = cb & 31;
    int tb = b * S_DIM + c * CHUNK;
    int r0 = rt * 64;
    __shared__ float As[64][65], Vs[64][65], Qs[64][65], Ms[64][65];
    int t = threadIdx.x;
    int tr = t >> 4, tc = t & 15;
#pragma unroll
    for (int i = 0; i < 16; i++) {
        int idx = t + i * 256; int rr = idx >> 6, cc2 = idx & 63;
        As[rr][cc2] = Abuf[(size_t)cb * 4096 + rr * 64 + cc2];
        Vs[rr][cc2] = kqv[(size_t)(tb + rr) * 768 + 512 + r0 + cc2];
    }
    __syncthreads();
    float acc[4][4] = {};
    for (int j = 0; j < 64; j++) {
        float aa[4], vv[4];
#pragma unroll
        for (int r = 0; r < 4; r++)  aa[r] = As[tr * 4 + r][j];
#pragma unroll
        for (int cc = 0; cc < 4; cc++) vv[cc] = Vs[j][tc * 4 + cc];
#pragma unroll
        for (int r = 0; r < 4; r++)
#pragma unroll
            for (int cc = 0; cc < 4; cc++) acc[r][cc] += aa[r] * vv[cc];
    }
    float acc2[4][4] = {};
    for (int kt = 0; kt < 4; kt++) {
        __syncthreads();
#pragma unroll
        for (int i = 0; i < 16; i++) {
            int idx = t + i * 256; int rr = idx >> 6, cc2 = idx & 63;
            Qs[rr][cc2] = kqv[(size_t)(tb + rr) * 768 + 256 + kt * 64 + cc2];
            Ms[rr][cc2] = states[(size_t)cb * 65536 + (size_t)(r0 + rr) * 256 + kt * 64 + cc2];
        }
        __syncthreads();
        for (int kk = 0; kk < 64; kk++) {
            float qq[4], mm[4];
#pragma unroll
            for (int r = 0; r < 4; r++)  qq[r] = Qs[tr * 4 + r][kk];
#pragma unroll
            for (int cc = 0; cc < 4; cc++) mm[cc] = Ms[tc * 4 + cc][kk];
#pragma unroll
            for (int r = 0; r < 4; r++)
#pragma unroll
                for (int cc = 0; cc < 4; cc++) acc2[r][cc] += qq[r] * mm[cc];
        }
    }
#pragma unroll
    for (int r = 0; r < 4; r++) {
#pragma unroll
        for (int cc = 0; cc < 4; cc++) {
            int i = tr * 4 + r;
            float val = acc[r][cc] + P[cb * 65 + i] * acc2[r][cc];
            ro[(size_t)(tb + i) * 256 + r0 + tc * 4 + cc] = f2bf(val);
        }
    }
}

// ---------------- split-K combine: out += partial ----------------
__global__ __launch_bounds__(256) void combine_k(float4* __restrict__ out,
                                                 const float4* __restrict__ part) {
    int i = blockIdx.x * 256 + threadIdx.x;
    float4 a = out[i], b = part[i];
    a.x += b.x; a.y += b.y; a.z += b.z; a.w += b.w;
    out[i] = a;
}

#define EPI_BIAS   0
#define EPI_RESID  1
#define EPI_GELU   2
#define EPI_SPART  3
#define EPI_SRESID 4

// ---------------- bf16 MFMA GEMM: 128-tile version (kqv / wout shapes) ----------------
// R6 structure: triple-buffered LDS + counted vmcnt + raw s_barrier.
template<int EPI, int BM, int MY, int SQH, int SQW>
__global__ __launch_bounds__(256) void gemm_bt(
    const u16* __restrict__ A, int lda,
    const u16* __restrict__ B, int ldb,
    const float* __restrict__ bias,
    const float* __restrict__ resid,
    float* __restrict__ outF, u16* __restrict__ outB,
    int ldc, int K, float* __restrict__ part)
{
    constexpr int MI = BM / 32;
    __shared__ u16 As[3][BM * 32];
    __shared__ u16 Bs[3][128 * 32];
    const int t = threadIdx.x;
    const int lane = t & 63;
    const int w = t >> 6;
    const int waveM = (w >> 1) * (BM / 2);
    const int waveN = (w & 1) * 64;

    int bx, by;
    if (MY == 0) {
        bx = blockIdx.x; by = blockIdx.y;
    } else {
        const u32 NX = gridDim.x;
        u32 flat = blockIdx.x + NX * blockIdx.y;
        u32 xcd = flat & 7;
        u32 local = flat >> 3;
        u32 perBand = (u32)SQH * NX;
        u32 band = local / perBand;
        u32 rem  = local - band * perBand;
        u32 sq   = rem / (SQH * SQW);
        u32 wloc = rem - sq * (SQH * SQW);
        u32 wy = wloc / SQW, wx = wloc - wy * SQW;
        by = xcd * MY + band * SQH + wy;
        bx = sq * SQW + wx;
    }

    const int m0 = by * BM;
    const int n0 = bx * 128;
    const size_t koff = (size_t)blockIdx.z * K;

    const int sr = t >> 2, scw = sw_slot(t);
    const u16* Ag0 = A + (size_t)(m0 + sr) * lda + koff + scw;
    const u16* Ag1 = A + (size_t)(m0 + 64 + sr) * lda + koff + scw;   // BM==128 only
    const u16* Bg0 = B + (size_t)(n0 + sr) * ldb + koff + scw;
    const u16* Bg1 = B + (size_t)(n0 + 64 + sr) * ldb + koff + scw;

    floatx4 acc[MI][4] = {};

    const int kc = lane >> 4;
    const int rsel = lane & 15;
    const int NK = K >> 5;

    gload_lds16(Ag0, As[0] + t * 8);
    if (BM == 128) gload_lds16(Ag1, As[0] + (t + 256) * 8);
    gload_lds16(Bg0, Bs[0] + t * 8);
    gload_lds16(Bg1, Bs[0] + (t + 256) * 8);
    gload_lds16(Ag0 + 32, As[1] + t * 8);
    if (BM == 128) gload_lds16(Ag1 + 32, As[1] + (t + 256) * 8);
    gload_lds16(Bg0 + 32, Bs[1] + t * 8);
    gload_lds16(Bg1 + 32, Bs[1] + (t + 256) * 8);
    if constexpr (BM == 128) { asm volatile("s_waitcnt vmcnt(4)" ::: "memory"); }
    else                     { asm volatile("s_waitcnt vmcnt(3)" ::: "memory"); }
    __builtin_amdgcn_s_barrier();
    __builtin_amdgcn_sched_barrier(0);

    int cur = 0, nx1 = 1, nx2 = 2;
    for (int kt = 0; kt < NK; kt++) {
        if (kt + 2 < NK) {
            const int kof = (kt + 2) * 32;
            u16* Ad = As[nx2];
            u16* Bd = Bs[nx2];
            gload_lds16(Ag0 + kof, Ad + t * 8);
            if (BM == 128) gload_lds16(Ag1 + kof, Ad + (t + 256) * 8);
            gload_lds16(Bg0 + kof, Bd + t * 8);
            gload_lds16(Bg1 + kof, Bd + (t + 256) * 8);
        }
        const u16* Ac = As[cur];
        const u16* Bc = Bs[cur];
        short8 af[MI], bfr[4];
#pragma unroll
        for (int i = 0; i < MI; i++)
            af[i] = *(const short8*)(Ac + sw_read(waveM + i * 16 + rsel, kc));
#pragma unroll
        for (int j = 0; j < 4; j++)
            bfr[j] = *(const short8*)(Bs[cur] + sw_read(waveN + j * 16 + rsel, kc));
#pragma unroll
        for (int i = 0; i < MI; i++)
#pragma unroll
            for (int j = 0; j < 4; j++)
                acc[i][j] = __builtin_amdgcn_mfma_f32_16x16x32_bf16(af[i], bfr[j], acc[i][j], 0, 0, 0);
        if (kt + 2 < NK) {
            if constexpr (BM == 128) { asm volatile("s_waitcnt vmcnt(4)" ::: "memory"); }
            else                     { asm volatile("s_waitcnt vmcnt(3)" ::: "memory"); }
        } else {
            asm volatile("s_waitcnt vmcnt(0)" ::: "memory");
        }
        __builtin_amdgcn_s_barrier();
        __builtin_amdgcn_sched_barrier(0);
        const int tmp = cur; cur = nx1; nx1 = nx2; nx2 = tmp;
    }

    const bool zmain = (blockIdx.z == 0);
    const int rbase = (lane >> 4) * 4;
#pragma unroll
    for (int i = 0; i < MI; i++) {
#pragma unroll
        for (int j = 0; j < 4; j++) {
            const int col = n0 + waveN + j * 16 + rsel;
            float bv = 0.0f;
            if (EPI == EPI_BIAS || EPI == EPI_RESID || EPI == EPI_GELU) bv = bias[col];
            if (EPI == EPI_SRESID && zmain) bv = bias[col];
#pragma unroll
            for (int r = 0; r < 4; r++) {
                const int row = m0 + waveM + i * 16 + rbase + r;
                const size_t oidx = (size_t)row * ldc + col;
                float v = acc[i][j][r] + bv;
                if (EPI == EPI_BIAS) {
                    outF[oidx] = v;
                } else if (EPI == EPI_RESID) {
                    outF[oidx] = v + resid[oidx];
                } else if (EPI == EPI_GELU) {
                    float gl = 0.5f * v * (1.0f + erff(v * 0.70710678118654752f));
                    outB[oidx] = f2bf(gl);
                } else if (EPI == EPI_SPART) {
                    (zmain ? outF : part)[oidx] = v;
                } else { // EPI_SRESID
                    if (zmain) outF[oidx] = v + resid[oidx];
                    else       part[oidx] = v;
                }
            }
        }
    }
}

// ---------------- bf16 MFMA GEMM: 256x256 deep-pipelined (FFN1 / FFN2) ----------------
// R7: 256^2 tile, BK=64 split into two 32-k-half phases, 8 waves (512 thr), 128KB LDS.
// Per phase: vmcnt(8) [own region's 4 loads are oldest of 12 outstanding] -> s_barrier
// [all waves' loads for this region landed] -> 12 ds_read_b128 -> issue next 4-load
// region -> lgkmcnt(0) -> setprio(1) 32 MFMA setprio(0). Counted vmcnt never drains
// to 0 mid-loop (T4); loads issued 2 phases (~600cy MFMA) before use. Region-reuse
// safety: a stage targets a region whose readers finished lgkmcnt(0) before the
// preceding phase barrier. Swizzle = same verified sw_slot/sw_read pair per
// [256][32] u16 kh-region (0 bank conflicts). MFMA:ds_read = 32:12 per phase and
// 131 FLOP/staged-byte (2x the 128^2 structure) attack the VALU-issue bound
// (R6 counters: VALUBusy 45.7% > MfmaUtil 24.7%).
__device__ __forceinline__ void g8_stage(const u16* As, const u16* Bs, int lda, int ldb,
                                         u16* la, u16* lb, int t, int ko) {
    gload_lds16(As + ko, la + t * 8);
    gload_lds16(As + (size_t)128 * lda + ko, la + 4096 + t * 8);
    gload_lds16(Bs + ko, lb + t * 8);
    gload_lds16(Bs + (size_t)128 * ldb + ko, lb + 4096 + t * 8);
}
__device__ __forceinline__ void g8_frags(const u16* LA, const u16* LB,
                                         int wm, int wn, int rsel, int kc,
                                         short8 (&af)[8], short8 (&bv)[4]) {
#pragma unroll
    for (int i = 0; i < 8; i++)
        af[i] = *(const short8*)(LA + sw_read(wm * 128 + i * 16 + rsel, kc));
#pragma unroll
    for (int j = 0; j < 4; j++)
        bv[j] = *(const short8*)(LB + sw_read(wn * 64 + j * 16 + rsel, kc));
}
__device__ __forceinline__ void g8_mfma(short8 (&af)[8], short8 (&bv)[4], floatx4 (&acc)[8][4]) {
    __builtin_amdgcn_s_setprio(1);
#pragma unroll
    for (int i = 0; i < 8; i++)
#pragma unroll
        for (int j = 0; j < 4; j++)
            acc[i][j] = __builtin_amdgcn_mfma_f32_16x16x32_bf16(af[i], bv[j], acc[i][j], 0, 0, 0);
    __builtin_amdgcn_s_setprio(0);
}

template<int EPI, int MY, int SQH, int SQW>
__global__ __launch_bounds__(512, 2) void gemm8(
    const u16* __restrict__ A, int lda,
    const u16* __restrict__ B, int ldb,
    const float* __restrict__ bias,
    const float* __restrict__ resid,
    float* __restrict__ outF, u16* __restrict__ outB,
    int ldc, int K, float* __restrict__ part)
{
    __shared__ u16 L[2][2][2][8192];   // [dbuf][op A=0/B=1][k-half][256*32] = 128 KiB
    const int t = threadIdx.x;
    const int lane = t & 63;
    const int w = t >> 6;
    const int wm = w >> 2;             // 2 wave-rows x 4 wave-cols
    const int wn = w & 3;
    const int kc = lane >> 4;
    const int rsel = lane & 15;

    int bx, by;
    {
        const u32 NX = gridDim.x;
        u32 flat = blockIdx.x + NX * blockIdx.y;
        u32 xcd = flat & 7;
        u32 local = flat >> 3;
        u32 perBand = (u32)SQH * NX;
        u32 band = local / perBand;
        u32 rem  = local - band * perBand;
        u32 sq   = rem / (SQH * SQW);
        u32 wloc = rem - sq * (SQH * SQW);
        u32 wy = wloc / SQW, wx = wloc - wy * SQW;
        by = xcd * MY + band * SQH + wy;
        bx = sq * SQW + wx;
    }
    const int m0 = by * 256;
    const int n0 = bx * 256;
    const size_t koff = (size_t)blockIdx.z * K;

    const int srow = t >> 2;           // staging row (0..127), li adds 128
    const int scw  = sw_slot(t);       // inverse-swizzled source column octet
    const u16* Asrc = A + (size_t)(m0 + srow) * lda + koff + scw;
    const u16* Bsrc = B + (size_t)(n0 + srow) * ldb + koff + scw;

    floatx4 acc[8][4] = {};
    const int NT = K >> 6;

    // prologue: groups [t0,kh0] [t0,kh1] [t1,kh0]
    g8_stage(Asrc, Bsrc, lda, ldb, &L[0][0][0][0], &L[0][1][0][0], t, 0);
    g8_stage(Asrc, Bsrc, lda, ldb, &L[0][0][1][0], &L[0][1][1][0], t, 32);
    if (NT > 1)
        g8_stage(Asrc, Bsrc, lda, ldb, &L[1][0][0][0], &L[1][1][0][0], t, 64);

    for (int tt = 0; tt + 1 < NT; ++tt) {
        const int cb = tt & 1;
        // ---- phase kh=0 : consume [tt,kh0], stage [tt+1,kh1] ----
        asm volatile("s_waitcnt vmcnt(8)" ::: "memory");
        __builtin_amdgcn_s_barrier();
        __builtin_amdgcn_sched_barrier(0);
        {
            short8 af[8], bv[4];
            g8_frags(&L[cb][0][0][0], &L[cb][1][0][0], wm, wn, rsel, kc, af, bv);
            g8_stage(Asrc, Bsrc, lda, ldb, &L[cb ^ 1][0][1][0], &L[cb ^ 1][1][1][0], t,
                     (tt + 1) * 64 + 32);
            asm volatile("s_waitcnt lgkmcnt(0)" ::: "memory");
            __builtin_amdgcn_sched_barrier(0);
            g8_mfma(af, bv, acc);
        }
        // ---- phase kh=1 : consume [tt,kh1], stage [tt+2,kh0] ----
        asm volatile("s_waitcnt vmcnt(8)" ::: "memory");
        __builtin_amdgcn_s_barrier();
        __builtin_amdgcn_sched_barrier(0);
        {
            short8 af[8], bv[4];
            g8_frags(&L[cb][0][1][0], &L[cb][1][1][0], wm, wn, rsel, kc, af, bv);
            if (tt + 2 < NT)
                g8_stage(Asrc, Bsrc, lda, ldb, &L[cb][0][0][0], &L[cb][1][0][0], t,
                         (tt + 2) * 64);
            asm volatile("s_waitcnt lgkmcnt(0)" ::: "memory");
            __builtin_amdgcn_sched_barrier(0);
            g8_mfma(af, bv, acc);
        }
    }
    // ---- tail tile NT-1: no staging; drain 4 -> 0 ----
    {
        const int cb = (NT - 1) & 1;
        asm volatile("s_waitcnt vmcnt(4)" ::: "memory");
        __builtin_amdgcn_s_barrier();
        __builtin_amdgcn_sched_barrier(0);
        {
            short8 af[8], bv[4];
            g8_frags(&L[cb][0][0][0], &L[cb][1][0][0], wm, wn, rsel, kc, af, bv);
            asm volatile("s_waitcnt lgkmcnt(0)" ::: "memory");
            __builtin_amdgcn_sched_barrier(0);
            g8_mfma(af, bv, acc);
        }
        asm volatile("s_waitcnt vmcnt(0)" ::: "memory");
        __builtin_amdgcn_s_barrier();
        __builtin_amdgcn_sched_barrier(0);
        {
            short8 af[8], bv[4];
            g8_frags(&L[cb][0][1][0], &L[cb][1][1][0], wm, wn, rsel, kc, af, bv);
            asm volatile("s_waitcnt lgkmcnt(0)" ::: "memory");
            __builtin_amdgcn_sched_barrier(0);
            g8_mfma(af, bv, acc);
        }
    }

    const bool zmain = (blockIdx.z == 0);
    const int rbase = kc * 4;
#pragma unroll
    for (int i = 0; i < 8; i++) {
#pragma unroll
        for (int j = 0; j < 4; j++) {
            const int col = n0 + wn * 64 + j * 16 + rsel;
            float bv = 0.0f;
            if (EPI == EPI_BIAS || EPI == EPI_RESID || EPI == EPI_GELU) bv = bias[col];
            if (EPI == EPI_SRESID && zmain) bv = bias[col];
#pragma unroll
            for (int r = 0; r < 4; r++) {
                const int row = m0 + wm * 128 + i * 16 + rbase + r;
                const size_t oidx = (size_t)row * ldc + col;
                float v = acc[i][j][r] + bv;
                if (EPI == EPI_BIAS) {
                    outF[oidx] = v;
                } else if (EPI == EPI_RESID) {
                    outF[oidx] = v + resid[oidx];
                } else if (EPI == EPI_GELU) {
                    float gl = 0.5f * v * (1.0f + erff(v * 0.70710678118654752f));
                    outB[oidx] = f2bf(gl);
                } else if (EPI == EPI_SPART) {
                    (zmain ? outF : part)[oidx] = v;
                } else { // EPI_SRESID
                    if (zmain) outF[oidx] = v + resid[oidx];
                    else       part[oidx] = v;
                }
            }
        }
    }
}

// ---------------- launch ----------------
extern "C" void kernel_launch(void* const* d_in, const int* in_sizes, int n_in,
                              void* d_out, int out_size, void* d_ws, size_t ws_size,
                              hipStream_t stream) {
    const float* x     = (const float*)d_in[0];
    const float* mem0  = (const float*)d_in[1];
    const float* w_k   = (const float*)d_in[2];
    const float* b_k   = (const float*)d_in[3];
    const float* w_q   = (const float*)d_in[4];
    const float* b_q   = (const float*)d_in[5];
    const float* w_v   = (const float*)d_in[6];
    const float* b_v   = (const float*)d_in[7];
    const float* w_out = (const float*)d_in[8];
    const float* b_out = (const float*)d_in[9];
    const float* w_gw  = (const float*)d_in[10];
    const float* b_gw  = (const float*)d_in[11];
    const float* w_gf  = (const float*)d_in[12];
    const float* b_gf  = (const float*)d_in[13];
    const float* ln1g  = (const float*)d_in[14];
    const float* ln1b  = (const float*)d_in[15];
    const float* ln2g  = (const float*)d_in[16];
    const float* ln2b  = (const float*)d_in[17];
    const float* w_f1  = (const float*)d_in[18];
    const float* b_f1  = (const float*)d_in[19];
    const float* w_f2  = (const float*)d_in[20];
    const float* b_f2  = (const float*)d_in[21];

    char* ws = (char*)d_ws;
    u16*   wkqv  = (u16*)(ws + OFF_WKQV);
    u16*   wout  = (u16*)(ws + OFF_WOUT);
    u16*   wf1   = (u16*)(ws + OFF_WF1);
    u16*   wf2   = (u16*)(ws + OFF_WF2);
    float* bkqv  = (float*)(ws + OFF_BKQV);
    float* beta  = (float*)(ws + OFF_BETA);
    float* decay = (float*)(ws + OFF_DECAY);
    float* P     = (float*)(ws + OFF_P);
    float* ww    = (float*)(ws + OFF_WW);
    float* Abuf  = (float*)(ws + OFF_ABUF);
    u16*   xn    = (u16*)(ws + OFF_XN);
    float* kqv   = (float*)(ws + OFF_KQV);
    float* kqvPB = (float*)(ws + OFF_T);
    float* T     = (float*)(ws + OFF_T);
    float* states= (float*)(ws + OFF_STATES);
    u16*   ro    = (u16*)(ws + OFF_RO);
    u16*   h     = (u16*)(ws + OFF_H);
    float* y1    = (float*)(ws + OFF_Y1);
    u16*   g     = (u16*)(ws + OFF_G);
    float* p2    = (float*)(ws + OFF_P2);

    float* out_x   = (float*)d_out;
    float* out_mem = out_x + (size_t)NTOK * E_DIM;

    convert_weights<<<9217, 256, 0, stream>>>(
        (const float4*)w_k, (const float4*)w_q, (const float4*)w_v,
        (const float4*)w_out, (const float4*)w_f1, (const float4*)w_f2,
        b_k, b_q, b_v,
        (uint2*)wkqv, (uint2*)wout, (uint2*)wf1, (uint2*)wf2, bkqv);

    ln1_gates<<<NTOK, 256, 0, stream>>>(x, ln1g, ln1b, w_gw, b_gw, w_gf, b_gf, xn, beta, decay);

    // k/q/v: split-K(2) full density (B fits L2 -> no tile swizzle needed)
    gemm_bt<EPI_SPART, 128, 0, 0, 0><<<dim3(6, 64, 2), 256, 0, stream>>>(
        xn, 1024, wkqv, 1024, nullptr, nullptr, kqv, nullptr, 768, 512, kqvPB);
    kqv_act<<<NTOK, 256, 0, stream>>>(kqv, kqvPB, bkqv);

    chunk_prep<<<NCB, 64, 0, stream>>>(beta, decay, P, ww);
    t_kernel<<<dim3(16, NCB), 256, 0, stream>>>(kqv, P, ww, T);
    mem_scan<<<1024, 256, 0, stream>>>(mem0, T, P, states, out_mem);
    qk_attn<<<NCB, 256, 0, stream>>>(kqv, P, ww, Abuf);
    readout_k<<<dim3(4, NCB), 256, 0, stream>>>(kqv, Abuf, states, P, ro);

    gemm_bt<EPI_RESID, 64, 0, 0, 0><<<dim3(8, 128), 256, 0, stream>>>(
        ro, 256, wout, 256, b_out, x, y1, nullptr, 1024, 256, nullptr);

    ln2_kernel<<<NTOK, 256, 0, stream>>>(y1, ln2g, ln2b, h);
    // FFN1: 256^2 deep pipeline; XCD bands of MY=4 m-tiles, 4x4 sub-squares (4MB/XCD L2)
    gemm8<EPI_GELU, 4, 4, 4><<<dim3(16, 32), 512, 0, stream>>>(
        h, 1024, wf1, 1024, b_f1, nullptr, nullptr, g, 4096, 1024, nullptr);
    // FFN2: 256^2 deep pipeline + split-K(2); 128 blocks/z -> 256 total (1/CU)
    gemm8<EPI_SRESID, 4, 4, 4><<<dim3(4, 32, 2), 512, 0, stream>>>(
        g, 4096, wf2, 4096, b_f2, y1, out_x, nullptr, 1024, 2048, p2);
    combine_k<<<8192, 256, 0, stream>>>((float4*)out_x, (const float4*)p2);
}

// Round 3
// 520.890 us; speedup vs baseline: 1.0164x; 1.0060x over previous
//
#include <hip/hip_runtime.h>
#include <stdint.h>

// ---------------- problem constants ----------------
#define E_DIM 1024
#define M_DIM 256
#define B_DIM 4
#define S_DIM 2048
#define NTOK  8192      // B*S
#define CHUNK 64
#define NCHUNK 32       // S / CHUNK
#define NCB   128       // B * NCHUNK

typedef unsigned short u16;
typedef unsigned int   u32;
typedef __attribute__((ext_vector_type(8))) short short8;
typedef __attribute__((ext_vector_type(4))) float floatx4;

// ---------------- workspace layout (bytes) ----------------
#define OFF_WKQV   ((size_t)0)            // 768*1024 bf16 = 1,572,864
#define OFF_WOUT   ((size_t)1572864)      // 1024*256 bf16 = 524,288
#define OFF_WF1    ((size_t)2097152)      // 4096*1024 bf16 = 8,388,608
#define OFF_WF2    ((size_t)10485760)     // 8,388,608
#define OFF_BKQV   ((size_t)18874368)     // 768 f32
#define OFF_BETA   ((size_t)18877440)     // 8192 f32
#define OFF_DECAY  ((size_t)18910208)     // 8192 f32
#define OFF_P      ((size_t)18942976)     // 128*65 f32
#define OFF_WW     ((size_t)18976256)     // 128*64 f32
#define OFF_ABUF   ((size_t)19009024)     // 128*64*64 f32 = 2,097,152
#define OFF_XN     ((size_t)21106176)     // 8192*1024 bf16 = 16,777,216  [h, ffn2-partial alias]
#define OFF_KQV    ((size_t)37883392)     // 8192*768 f32 = 25,165,824    [kqv split-K partial A]
#define OFF_T      ((size_t)63049216)     // 128*65536 f32 = 33,554,432   [kqv partial B, then T, then y1]
#define OFF_STATES ((size_t)96603648)     // 128*65536 f32 = 33,554,432   [g starts here]
#define OFF_RO     ((size_t)130158080)    // 8192*256 bf16 = 4,194,304
#define OFF_H      OFF_XN                 // 8192*1024 bf16 (xn dead after kqv gemm)
#define OFF_Y1     OFF_T                  // 8192*1024 f32 (T dead after mem_scan)
#define OFF_G      OFF_STATES             // 8192*4096 bf16 = 67,108,864 (states+ro dead)
#define OFF_P2     OFF_XN                 // 8192*1024 f32 FFN2 split-K partial (h/kqv dead)

// ---------------- helpers ----------------
__device__ __forceinline__ u16 f2bf(float f) {
    union { float f; u32 u; } a; a.f = f;
    u32 u = a.u;
    return (u16)((u + 0x7fffu + ((u >> 16) & 1u)) >> 16);
}
__device__ __forceinline__ u32 pack2bf(float a, float b) {
    return (u32)f2bf(a) | ((u32)f2bf(b) << 16);
}
__device__ __forceinline__ float sigmoidf_(float x) { return 1.0f / (1.0f + expf(-x)); }

// async global->LDS, 16 bytes per lane; LDS dest contiguous in lane order.
__device__ __forceinline__ void gload_lds16(const u16* g, u16* l) {
    __builtin_amdgcn_global_load_lds((const __attribute__((address_space(1))) void*)g,
                                     (__attribute__((address_space(3))) void*)l, 16, 0, 0);
}

// XOR-swizzle for a [rows][32] u16 region (verified: SQ_LDS_BANK_CONFLICT -> 0)
__device__ __forceinline__ int sw_slot(int idx) {
    return ((idx & 3) ^ ((idx >> 3) & 3)) * 8;
}
__device__ __forceinline__ int sw_read(int row, int kc) {
    return row * 32 + ((kc ^ ((row >> 1) & 3)) << 3);
}

// two-value block reduction across 256 threads (4 waves)
__device__ __forceinline__ void block_reduce_2(float& a, float& b, float* red, int t) {
#pragma unroll
    for (int o = 32; o > 0; o >>= 1) { a += __shfl_xor(a, o); b += __shfl_xor(b, o); }
    if ((t & 63) == 0) { red[t >> 6] = a; red[4 + (t >> 6)] = b; }
    __syncthreads();
    a = red[0] + red[1] + red[2] + red[3];
    b = red[4] + red[5] + red[6] + red[7];
    __syncthreads();
}

// ---------------- unified weight conversion ----------------
__device__ __forceinline__ uint2 cvt4(float4 v) {
    uint2 o; o.x = pack2bf(v.x, v.y); o.y = pack2bf(v.z, v.w); return o;
}
__global__ void convert_weights(const float4* __restrict__ wk, const float4* __restrict__ wq,
                                const float4* __restrict__ wv, const float4* __restrict__ wo,
                                const float4* __restrict__ wf1in, const float4* __restrict__ wf2in,
                                const float* __restrict__ bk, const float* __restrict__ bq,
                                const float* __restrict__ bv,
                                uint2* __restrict__ wkqv, uint2* __restrict__ wout,
                                uint2* __restrict__ wf1, uint2* __restrict__ wf2,
                                float* __restrict__ bkqv) {
    int b = blockIdx.x, t = threadIdx.x;
    if (b < 768) {
        int i = b * 256 + t;
        int sec = i >> 16, off = i & 65535;
        const float4* s = (sec == 0) ? wk : ((sec == 1) ? wq : wv);
        wkqv[i] = cvt4(s[off]);
    } else if (b < 1024) {
        int i = (b - 768) * 256 + t;
        wout[i] = cvt4(wo[i]);
    } else if (b < 5120) {
        int i = (b - 1024) * 256 + t;
        wf1[i] = cvt4(wf1in[i]);
    } else if (b < 9216) {
        int i = (b - 5120) * 256 + t;
        wf2[i] = cvt4(wf2in[i]);
    } else {
        bkqv[t] = bk[t]; bkqv[256 + t] = bq[t]; bkqv[512 + t] = bv[t];
    }
}

// ---------------- LN kernels ----------------
__global__ __launch_bounds__(256) void ln1_gates(
    const float* __restrict__ x, const float* __restrict__ g, const float* __restrict__ b,
    const float* __restrict__ wgw, const float* __restrict__ bgw,
    const float* __restrict__ wgf, const float* __restrict__ bgf,
    u16* __restrict__ xn, float* __restrict__ beta, float* __restrict__ decay)
{
    __shared__ float red[8];
    const int row = blockIdx.x;
    const int t = threadIdx.x;
    const float4 v = ((const float4*)(x + (size_t)row * E_DIM))[t];
    float s  = v.x + v.y + v.z + v.w;
    float ss = v.x * v.x + v.y * v.y + v.z * v.z + v.w * v.w;
    block_reduce_2(s, ss, red, t);
    const float mean = s * (1.0f / E_DIM);
    const float var  = ss * (1.0f / E_DIM) - mean * mean;
    const float rstd = rsqrtf(var + 1e-5f);
    const float4 gg = ((const float4*)g)[t];
    const float4 bb = ((const float4*)b)[t];
    float4 xnv;
    xnv.x = (v.x - mean) * rstd * gg.x + bb.x;
    xnv.y = (v.y - mean) * rstd * gg.y + bb.y;
    xnv.z = (v.z - mean) * rstd * gg.z + bb.z;
    xnv.w = (v.w - mean) * rstd * gg.w + bb.w;
    uint2 o; o.x = pack2bf(xnv.x, xnv.y); o.y = pack2bf(xnv.z, xnv.w);
    ((uint2*)(xn + (size_t)row * E_DIM))[t] = o;
    const float4 w1 = ((const float4*)wgw)[t];
    const float4 w2 = ((const float4*)wgf)[t];
    float dg = xnv.x * w1.x + xnv.y * w1.y + xnv.z * w1.z + xnv.w * w1.w;
    float df = xnv.x * w2.x + xnv.y * w2.y + xnv.z * w2.z + xnv.w * w2.w;
    block_reduce_2(dg, df, red, t);
    if (t == 0) {
        beta[row]  = sigmoidf_(dg + bgw[0]);
        decay[row] = sigmoidf_(df + bgf[0]);
    }
}

__global__ __launch_bounds__(256) void ln2_kernel(
    const float* __restrict__ y1, const float* __restrict__ g, const float* __restrict__ b,
    u16* __restrict__ h)
{
    __shared__ float red[8];
    const int row = blockIdx.x;
    const int t = threadIdx.x;
    const float4 v = ((const float4*)(y1 + (size_t)row * E_DIM))[t];
    float s  = v.x + v.y + v.z + v.w;
    float ss = v.x * v.x + v.y * v.y + v.z * v.z + v.w * v.w;
    block_reduce_2(s, ss, red, t);
    const float mean = s * (1.0f / E_DIM);
    const float var  = ss * (1.0f / E_DIM) - mean * mean;
    const float rstd = rsqrtf(var + 1e-5f);
    const float4 gg = ((const float4*)g)[t];
    const float4 bb = ((const float4*)b)[t];
    float4 xnv;
    xnv.x = (v.x - mean) * rstd * gg.x + bb.x;
    xnv.y = (v.y - mean) * rstd * gg.y + bb.y;
    xnv.z = (v.z - mean) * rstd * gg.z + bb.z;
    xnv.w = (v.w - mean) * rstd * gg.w + bb.w;
    uint2 o; o.x = pack2bf(xnv.x, xnv.y); o.y = pack2bf(xnv.z, xnv.w);
    ((uint2*)(h + (size_t)row * E_DIM))[t] = o;
}

// ---------------- k/q/v: combine split-K partials + bias, then activations ----------------
__global__ __launch_bounds__(256) void kqv_act(float* __restrict__ pA,
                                               const float* __restrict__ pB,
                                               const float* __restrict__ bias) {
    __shared__ float red[8];
    const int row = blockIdx.x;
    const int t = threadIdx.x;
    float* p = pA + (size_t)row * 768;
    const float* q = pB + (size_t)row * 768;
    float kv = p[t]       + q[t]       + bias[t];
    float qv = p[256 + t] + q[256 + t] + bias[256 + t];
    float vv = p[512 + t] + q[512 + t] + bias[512 + t];
    float sk = kv * kv, sq = qv * qv;
    block_reduce_2(sk, sq, red, t);
    float nk = fmaxf(sqrtf(sk), 1e-12f);
    float nq = fmaxf(sqrtf(sq), 1e-12f);
    p[t]       = kv / nk;
    p[256 + t] = qv / nq;
    p[512 + t] = tanhf(vv);
}

// ---------------- chunk prep ----------------
__global__ void chunk_prep(const float* __restrict__ beta, const float* __restrict__ decay,
                           float* __restrict__ P, float* __restrict__ ww) {
    int cb = blockIdx.x;
    int b = cb >> 5, c = cb & 31;
    int tb = b * S_DIM + c * CHUNK;
    int j = threadIdx.x;
    __shared__ float d[64], bt[64], Ps[65];
    d[j]  = decay[tb + j];
    bt[j] = beta[tb + j];
    __syncthreads();
    if (j == 0) {
        float p = 1.0f; Ps[0] = 1.0f;
        for (int i = 0; i < 64; i++) { p *= d[i]; Ps[i + 1] = p; }
    }
    __syncthreads();
    P[cb * 65 + j] = Ps[j];
    if (j == 0) P[cb * 65 + 64] = Ps[64];
    ww[cb * 64 + j] = bt[j] / Ps[j + 1];
}

// ---------------- per-chunk state increment ----------------
__global__ __launch_bounds__(256) void t_kernel(const float* __restrict__ kqv,
                                                const float* __restrict__ P,
                                                const float* __restrict__ ww,
                                                float* __restrict__ T) {
    int cb = blockIdx.y;
    int tile = blockIdx.x;
    int r0 = (tile >> 2) * 64, c0 = (tile & 3) * 64;
    int b = cb >> 5, c = cb & 31;
    int tb = b * S_DIM + c * CHUNK;
    float p64 = P[cb * 65 + 64];
    __shared__ float Vs[64][65], Ks[64][65];
    int t = threadIdx.x;
#pragma unroll
    for (int i = 0; i < 16; i++) {
        int idx = t + i * 256; int j = idx >> 6, col = idx & 63;
        float sc = ww[cb * 64 + j] * p64;
        Vs[j][col] = kqv[(size_t)(tb + j) * 768 + 512 + r0 + col] * sc;
        Ks[j][col] = kqv[(size_t)(tb + j) * 768 + 0   + c0 + col];
    }
    __syncthreads();
    int tr = t >> 4, tc = t & 15;
    float a[4][4] = {};
    for (int j = 0; j < 64; j++) {
        float vv[4], kk[4];
#pragma unroll
        for (int r = 0; r < 4; r++)  vv[r] = Vs[j][tr * 4 + r];
#pragma unroll
        for (int cc = 0; cc < 4; cc++) kk[cc] = Ks[j][tc * 4 + cc];
#pragma unroll
        for (int r = 0; r < 4; r++)
#pragma unroll
            for (int cc = 0; cc < 4; cc++) a[r][cc] += vv[r] * kk[cc];
    }
#pragma unroll
    for (int r = 0; r < 4; r++)
#pragma unroll
        for (int cc = 0; cc < 4; cc++)
            T[(size_t)cb * 65536 + (size_t)(r0 + tr * 4 + r) * 256 + (c0 + tc * 4 + cc)] = a[r][cc];
}

// ---------------- element-parallel chunk scan ----------------
__global__ void mem_scan(const float* __restrict__ mem0, const float* __restrict__ T,
                         const float* __restrict__ P, float* __restrict__ states,
                         float* __restrict__ memOut) {
    int gid = blockIdx.x * 256 + threadIdx.x;
    int b = gid >> 16; int e = gid & 65535;
    float s = mem0[gid];
    for (int c = 0; c < NCHUNK; c++) {
        int cb = b * NCHUNK + c;
        states[(size_t)cb * 65536 + e] = s;
        s = P[cb * 65 + 64] * s + T[(size_t)cb * 65536 + e];
    }
    memOut[gid] = s;
}

// ---------------- intra-chunk attention matrix ----------------
__global__ __launch_bounds__(256) void qk_attn(const float* __restrict__ kqv,
                                               const float* __restrict__ P,
                                               const float* __restrict__ ww,
                                               float* __restrict__ Abuf) {
    int cb = blockIdx.x;
    int b = cb >> 5, c = cb & 31;
    int tb = b * S_DIM + c * CHUNK;
    __shared__ float Qs[64][65], Ks[64][65];
    int t = threadIdx.x;
    int tr = t >> 4, tc = t & 15;
    float acc[4][4] = {};
    for (int kt = 0; kt < 4; kt++) {
        __syncthreads();
#pragma unroll
        for (int i = 0; i < 16; i++) {
            int idx = t + i * 256; int rr = idx >> 6, cc2 = idx & 63;
            Qs[rr][cc2] = kqv[(size_t)(tb + rr) * 768 + 256 + kt * 64 + cc2];
            Ks[rr][cc2] = kqv[(size_t)(tb + rr) * 768 + 0   + kt * 64 + cc2];
        }
        __syncthreads();
        for (int kk = 0; kk < 64; kk++) {
            float qq[4], kx[4];
#pragma unroll
            for (int r = 0; r < 4; r++)  qq[r] = Qs[tr * 4 + r][kk];
#pragma unroll
            for (int cc = 0; cc < 4; cc++) kx[cc] = Ks[tc * 4 + cc][kk];
#pragma unroll
            for (int r = 0; r < 4; r++)
#pragma unroll
                for (int cc = 0; cc < 4; cc++) acc[r][cc] += qq[r] * kx[cc];
        }
    }
#pragma unroll
    for (int r = 0; r < 4; r++) {
#pragma unroll
        for (int cc = 0; cc < 4; cc++) {
            int i = tr * 4 + r, j = tc * 4 + cc;
            float v = (j < i) ? acc[r][cc] * (P[cb * 65 + i] * ww[cb * 64 + j]) : 0.0f;
            Abuf[(size_t)cb * 4096 + i * 64 + j] = v;
        }
    }
}

// ---------------- readout ----------------
__global__ __launch_bounds__(256) void readout_k(const float* __restrict__ kqv,
                                                 const float* __restrict__ Abuf,
                                                 const float* __restrict__ states,
                                                 const float* __restrict__ P,
                                                 u16* __restrict__ ro) {
    int cb = blockIdx.y;
    int rt = blockIdx.x;
    int b = cb >> 5, c = cb & 31;
    int tb = b * S_DIM + c * CHUNK;
    int r0 = rt * 64;
    __shared__ float As[64][65], Vs[64][65], Qs[64][65], Ms[64][65];
    int t = threadIdx.x;
    int tr = t >> 4, tc = t & 15;
#pragma unroll
    for (int i = 0; i < 16; i++) {
        int idx = t + i * 256; int rr = idx >> 6, cc2 = idx & 63;
        As[rr][cc2] = Abuf[(size_t)cb * 4096 + rr * 64 + cc2];
        Vs[rr][cc2] = kqv[(size_t)(tb + rr) * 768 + 512 + r0 + cc2];
    }
    __syncthreads();
    float acc[4][4] = {};
    for (int j = 0; j < 64; j++) {
        float aa[4], vv[4];
#pragma unroll
        for (int r = 0; r < 4; r++)  aa[r] = As[tr * 4 + r][j];
#pragma unroll
        for (int cc = 0; cc < 4; cc++) vv[cc] = Vs[j][tc * 4 + cc];
#pragma unroll
        for (int r = 0; r < 4; r++)
#pragma unroll
            for (int cc = 0; cc < 4; cc++) acc[r][cc] += aa[r] * vv[cc];
    }
    float acc2[4][4] = {};
    for (int kt = 0; kt < 4; kt++) {
        __syncthreads();
#pragma unroll
        for (int i = 0; i < 16; i++) {
            int idx = t + i * 256; int rr = idx >> 6, cc2 = idx & 63;
            Qs[rr][cc2] = kqv[(size_t)(tb + rr) * 768 + 256 + kt * 64 + cc2];
            Ms[rr][cc2] = states[(size_t)cb * 65536 + (size_t)(r0 + rr) * 256 + kt * 64 + cc2];
        }
        __syncthreads();
        for (int kk = 0; kk < 64; kk++) {
            float qq[4], mm[4];
#pragma unroll
            for (int r = 0; r < 4; r++)  qq[r] = Qs[tr * 4 + r][kk];
#pragma unroll
            for (int cc = 0; cc < 4; cc++) mm[cc] = Ms[tc * 4 + cc][kk];
#pragma unroll
            for (int r = 0; r < 4; r++)
#pragma unroll
                for (int cc = 0; cc < 4; cc++) acc2[r][cc] += qq[r] * mm[cc];
        }
    }
#pragma unroll
    for (int r = 0; r < 4; r++) {
#pragma unroll
        for (int cc = 0; cc < 4; cc++) {
            int i = tr * 4 + r;
            float val = acc[r][cc] + P[cb * 65 + i] * acc2[r][cc];
            ro[(size_t)(tb + i) * 256 + r0 + tc * 4 + cc] = f2bf(val);
        }
    }
}

// ---------------- split-K combine: out += partial ----------------
__global__ __launch_bounds__(256) void combine_k(float4* __restrict__ out,
                                                 const float4* __restrict__ part) {
    int i = blockIdx.x * 256 + threadIdx.x;
    float4 a = out[i], b = part[i];
    a.x += b.x; a.y += b.y; a.z += b.z; a.w += b.w;
    out[i] = a;
}

#define EPI_BIAS   0
#define EPI_RESID  1
#define EPI_GELU   2
#define EPI_SPART  3
#define EPI_SRESID 4

// ---------------- bf16 MFMA GEMM: 128-tile (kqv / wout) ----------------
// R8: reverted to the R0 2-buffer structure. R1's 3-buf variant cost these
// short-K GEMMs ~26us: 48KB LDS cut occupancy 5->3 blocks/CU (kqv NK=16,
// wout NK=8 are latency/prologue-bound and live off TLP, not pipelining).
template<int EPI, int BM, int MY, int SQH, int SQW>
__global__ __launch_bounds__(256) void gemm_bt(
    const u16* __restrict__ A, int lda,
    const u16* __restrict__ B, int ldb,
    const float* __restrict__ bias,
    const float* __restrict__ resid,
    float* __restrict__ outF, u16* __restrict__ outB,
    int ldc, int K, float* __restrict__ part)
{
    constexpr int MI = BM / 32;
    __shared__ u16 As[2][BM * 32];
    __shared__ u16 Bs[2][128 * 32];
    const int t = threadIdx.x;
    const int lane = t & 63;
    const int w = t >> 6;
    const int waveM = (w >> 1) * (BM / 2);
    const int waveN = (w & 1) * 64;

    int bx, by;
    if (MY == 0) {
        bx = blockIdx.x; by = blockIdx.y;
    } else {
        const u32 NX = gridDim.x;
        u32 flat = blockIdx.x + NX * blockIdx.y;
        u32 xcd = flat & 7;
        u32 local = flat >> 3;
        u32 perBand = (u32)SQH * NX;
        u32 band = local / perBand;
        u32 rem  = local - band * perBand;
        u32 sq   = rem / (SQH * SQW);
        u32 wloc = rem - sq * (SQH * SQW);
        u32 wy = wloc / SQW, wx = wloc - wy * SQW;
        by = xcd * MY + band * SQH + wy;
        bx = sq * SQW + wx;
    }

    const int m0 = by * BM;
    const int n0 = bx * 128;
    const size_t koff = (size_t)blockIdx.z * K;

    const int sr = t >> 2, scw = sw_slot(t);
    const u16* Ag0 = A + (size_t)(m0 + sr) * lda + koff + scw;
    const u16* Ag1 = A + (size_t)(m0 + 64 + sr) * lda + koff + scw;   // BM==128 only
    const u16* Bg0 = B + (size_t)(n0 + sr) * ldb + koff + scw;
    const u16* Bg1 = B + (size_t)(n0 + 64 + sr) * ldb + koff + scw;

    floatx4 acc[MI][4] = {};

    const int kc = lane >> 4;
    const int rsel = lane & 15;
    const int NK = K >> 5;

    gload_lds16(Ag0, As[0] + t * 8);
    if (BM == 128) gload_lds16(Ag1, As[0] + (t + 256) * 8);
    gload_lds16(Bg0, Bs[0] + t * 8);
    gload_lds16(Bg1, Bs[0] + (t + 256) * 8);

    for (int kt = 0; kt < NK; kt++) {
        __syncthreads();
        const int cur = kt & 1;
        if (kt + 1 < NK) {
            const int kof = (kt + 1) * 32;
            gload_lds16(Ag0 + kof, As[cur ^ 1] + t * 8);
            if (BM == 128) gload_lds16(Ag1 + kof, As[cur ^ 1] + (t + 256) * 8);
            gload_lds16(Bg0 + kof, Bs[cur ^ 1] + t * 8);
            gload_lds16(Bg1 + kof, Bs[cur ^ 1] + (t + 256) * 8);
        }
        short8 af[MI], bfr[4];
#pragma unroll
        for (int i = 0; i < MI; i++)
            af[i] = *(const short8*)(As[cur] + sw_read(waveM + i * 16 + rsel, kc));
#pragma unroll
        for (int j = 0; j < 4; j++)
            bfr[j] = *(const short8*)(Bs[cur] + sw_read(waveN + j * 16 + rsel, kc));
#pragma unroll
        for (int i = 0; i < MI; i++)
#pragma unroll
            for (int j = 0; j < 4; j++)
                acc[i][j] = __builtin_amdgcn_mfma_f32_16x16x32_bf16(af[i], bfr[j], acc[i][j], 0, 0, 0);
    }

    const bool zmain = (blockIdx.z == 0);
    const int rbase = (lane >> 4) * 4;
#pragma unroll
    for (int i = 0; i < MI; i++) {
#pragma unroll
        for (int j = 0; j < 4; j++) {
            const int col = n0 + waveN + j * 16 + rsel;
            float bv = 0.0f;
            if (EPI == EPI_BIAS || EPI == EPI_RESID || EPI == EPI_GELU) bv = bias[col];
            if (EPI == EPI_SRESID && zmain) bv = bias[col];
#pragma unroll
            for (int r = 0; r < 4; r++) {
                const int row = m0 + waveM + i * 16 + rbase + r;
                const size_t oidx = (size_t)row * ldc + col;
                float v = acc[i][j][r] + bv;
                if (EPI == EPI_BIAS) {
                    outF[oidx] = v;
                } else if (EPI == EPI_RESID) {
                    outF[oidx] = v + resid[oidx];
                } else if (EPI == EPI_GELU) {
                    float gl = 0.5f * v * (1.0f + erff(v * 0.70710678118654752f));
                    outB[oidx] = f2bf(gl);
                } else if (EPI == EPI_SPART) {
                    (zmain ? outF : part)[oidx] = v;
                } else { // EPI_SRESID
                    if (zmain) outF[oidx] = v + resid[oidx];
                    else       part[oidx] = v;
                }
            }
        }
    }
}

// ---------------- bf16 MFMA GEMM: 256x256 deep-pipelined (FFN1 / FFN2) ----------------
// R8: certify-AHEAD phase ordering (the m201 overlap). Region r = one 32-k-half
// of A+B (4 gload_lds), slot = r mod 4, 128KB LDS. Phase p:
//   [12 ds_read region p]           <- data certified at phase p-1 (vmcnt+barrier)
//   [vmcnt(4): certify region p+1]  <- counted; region p+2 stays in flight (T4)
//   [s_barrier]                     <- absorbs LDS read-drain + wave jitter
//   [stage region p+3]              <- slot (p-1)&3; all waves read it by now
//   [lgkmcnt(0)] [setprio 32 MFMA]
// vs R7 (reads AFTER barrier): the per-phase LDS drain (96KB/CU, ~400cy) was
// serial before every MFMA cluster -> MfmaUtil 28%, 2ph-level perf (m248).
// Race-safety: region p's staging writes were vmcnt'd by EVERY wave before the
// p-1 barrier -> top-of-phase reads see complete data. Stage target slot was
// last read at phase p-1; every wave's p-1 reads finished (lgkmcnt 0) before
// it reached phase p's barrier.
__device__ __forceinline__ void g8_frags(const u16* LA, const u16* LB,
                                         int wm, int wn, int rsel, int kc,
                                         short8 (&af)[8], short8 (&bv)[4]) {
#pragma unroll
    for (int i = 0; i < 8; i++)
        af[i] = *(const short8*)(LA + sw_read(wm * 128 + i * 16 + rsel, kc));
#pragma unroll
    for (int j = 0; j < 4; j++)
        bv[j] = *(const short8*)(LB + sw_read(wn * 64 + j * 16 + rsel, kc));
}
__device__ __forceinline__ void g8_mfma(short8 (&af)[8], short8 (&bv)[4], floatx4 (&acc)[8][4]) {
    __builtin_amdgcn_s_setprio(1);
#pragma unroll
    for (int i = 0; i < 8; i++)
#pragma unroll
        for (int j = 0; j < 4; j++)
            acc[i][j] = __builtin_amdgcn_mfma_f32_16x16x32_bf16(af[i], bv[j], acc[i][j], 0, 0, 0);
    __builtin_amdgcn_s_setprio(0);
}

template<int EPI, int MY, int SQH, int SQW>
__global__ __launch_bounds__(512, 2) void gemm8(
    const u16* __restrict__ A, int lda,
    const u16* __restrict__ B, int ldb,
    const float* __restrict__ bias,
    const float* __restrict__ resid,
    float* __restrict__ outF, u16* __restrict__ outB,
    int ldc, int K, float* __restrict__ part)
{
    __shared__ u16 L[4][2][8192];      // [slot][op A=0/B=1][256*32] = 128 KiB
    const int t = threadIdx.x;
    const int lane = t & 63;
    const int w = t >> 6;
    const int wm = w >> 2;             // 2 wave-rows x 4 wave-cols
    const int wn = w & 3;
    const int kc = lane >> 4;
    const int rsel = lane & 15;

    int bx, by;
    {
        const u32 NX = gridDim.x;
        u32 flat = blockIdx.x + NX * blockIdx.y;
        u32 xcd = flat & 7;
        u32 local = flat >> 3;
        u32 perBand = (u32)SQH * NX;
        u32 band = local / perBand;
        u32 rem  = local - band * perBand;
        u32 sq   = rem / (SQH * SQW);
        u32 wloc = rem - sq * (SQH * SQW);
        u32 wy = wloc / SQW, wx = wloc - wy * SQW;
        by = xcd * MY + band * SQH + wy;
        bx = sq * SQW + wx;
    }
    const int m0 = by * 256;
    const int n0 = bx * 256;
    const size_t koff = (size_t)blockIdx.z * K;

    const int srow = t >> 2;           // staging row (0..127); +128 for second half
    const int scw  = sw_slot(t);       // inverse-swizzled source column octet
    const u16* Asrc = A + (size_t)(m0 + srow) * lda + koff + scw;
    const u16* Bsrc = B + (size_t)(n0 + srow) * ldb + koff + scw;

    floatx4 acc[8][4] = {};
    const int NR = (K >> 5);           // regions (32-k-halves)

    // stage region r (4 x global_load_lds) into slot r&3
    auto STAGE = [&](int r) {
        const int ko = r * 32;
        u16* la = &L[r & 3][0][0];
        u16* lb = &L[r & 3][1][0];
        gload_lds16(Asrc + ko, la + t * 8);
        gload_lds16(Asrc + (size_t)128 * lda + ko, la + 4096 + t * 8);
        gload_lds16(Bsrc + ko, lb + t * 8);
        gload_lds16(Bsrc + (size_t)128 * ldb + ko, lb + 4096 + t * 8);
    };

    // prologue: regions 0,1,2 in flight; certify region 0
    STAGE(0); STAGE(1); STAGE(2);
    asm volatile("s_waitcnt vmcnt(8)" ::: "memory");
    __builtin_amdgcn_s_barrier();
    __builtin_amdgcn_sched_barrier(0);

    for (int p = 0; p < NR; ++p) {
        // 1) reads of region p (certified at previous phase's vmcnt+barrier)
        short8 af[8], bv[4];
        g8_frags(&L[p & 3][0][0], &L[p & 3][1][0], wm, wn, rsel, kc, af, bv);
        // 2) certify region p+1 for the NEXT phase (counted: p+2 stays in flight)
        if (p + 1 < NR) {
            if (p + 2 < NR) { asm volatile("s_waitcnt vmcnt(4)" ::: "memory"); }
            else            { asm volatile("s_waitcnt vmcnt(0)" ::: "memory"); }
        }
        __builtin_amdgcn_s_barrier();
        __builtin_amdgcn_sched_barrier(0);
        // 3) stage region p+3 into the slot all waves just finished reading
        if (p + 3 < NR) STAGE(p + 3);
        // 4) own reads complete -> compute
        asm volatile("s_waitcnt lgkmcnt(0)" ::: "memory");
        __builtin_amdgcn_sched_barrier(0);
        g8_mfma(af, bv, acc);
    }

    const bool zmain = (blockIdx.z == 0);
    const int rbase = kc * 4;
#pragma unroll
    for (int i = 0; i < 8; i++) {
#pragma unroll
        for (int j = 0; j < 4; j++) {
            const int col = n0 + wn * 64 + j * 16 + rsel;
            float bvv = 0.0f;
            if (EPI == EPI_BIAS || EPI == EPI_RESID || EPI == EPI_GELU) bvv = bias[col];
            if (EPI == EPI_SRESID && zmain) bvv = bias[col];
#pragma unroll
            for (int r = 0; r < 4; r++) {
                const int row = m0 + wm * 128 + i * 16 + rbase + r;
                const size_t oidx = (size_t)row * ldc + col;
                float v = acc[i][j][r] + bvv;
                if (EPI == EPI_BIAS) {
                    outF[oidx] = v;
                } else if (EPI == EPI_RESID) {
                    outF[oidx] = v + resid[oidx];
                } else if (EPI == EPI_GELU) {
                    float gl = 0.5f * v * (1.0f + erff(v * 0.70710678118654752f));
                    outB[oidx] = f2bf(gl);
                } else if (EPI == EPI_SPART) {
                    (zmain ? outF : part)[oidx] = v;
                } else { // EPI_SRESID
                    if (zmain) outF[oidx] = v + resid[oidx];
                    else       part[oidx] = v;
                }
            }
        }
    }
}

// ---------------- launch ----------------
extern "C" void kernel_launch(void* const* d_in, const int* in_sizes, int n_in,
                              void* d_out, int out_size, void* d_ws, size_t ws_size,
                              hipStream_t stream) {
    const float* x     = (const float*)d_in[0];
    const float* mem0  = (const float*)d_in[1];
    const float* w_k   = (const float*)d_in[2];
    const float* b_k   = (const float*)d_in[3];
    const float* w_q   = (const float*)d_in[4];
    const float* b_q   = (const float*)d_in[5];
    const float* w_v   = (const float*)d_in[6];
    const float* b_v   = (const float*)d_in[7];
    const float* w_out = (const float*)d_in[8];
    const float* b_out = (const float*)d_in[9];
    const float* w_gw  = (const float*)d_in[10];
    const float* b_gw  = (const float*)d_in[11];
    const float* w_gf  = (const float*)d_in[12];
    const float* b_gf  = (const float*)d_in[13];
    const float* ln1g  = (const float*)d_in[14];
    const float* ln1b  = (const float*)d_in[15];
    const float* ln2g  = (const float*)d_in[16];
    const float* ln2b  = (const float*)d_in[17];
    const float* w_f1  = (const float*)d_in[18];
    const float* b_f1  = (const float*)d_in[19];
    const float* w_f2  = (const float*)d_in[20];
    const float* b_f2  = (const float*)d_in[21];

    char* ws = (char*)d_ws;
    u16*   wkqv  = (u16*)(ws + OFF_WKQV);
    u16*   wout  = (u16*)(ws + OFF_WOUT);
    u16*   wf1   = (u16*)(ws + OFF_WF1);
    u16*   wf2   = (u16*)(ws + OFF_WF2);
    float* bkqv  = (float*)(ws + OFF_BKQV);
    float* beta  = (float*)(ws + OFF_BETA);
    float* decay = (float*)(ws + OFF_DECAY);
    float* P     = (float*)(ws + OFF_P);
    float* ww    = (float*)(ws + OFF_WW);
    float* Abuf  = (float*)(ws + OFF_ABUF);
    u16*   xn    = (u16*)(ws + OFF_XN);
    float* kqv   = (float*)(ws + OFF_KQV);
    float* kqvPB = (float*)(ws + OFF_T);
    float* T     = (float*)(ws + OFF_T);
    float* states= (float*)(ws + OFF_STATES);
    u16*   ro    = (u16*)(ws + OFF_RO);
    u16*   h     = (u16*)(ws + OFF_H);
    float* y1    = (float*)(ws + OFF_Y1);
    u16*   g     = (u16*)(ws + OFF_G);
    float* p2    = (float*)(ws + OFF_P2);

    float* out_x   = (float*)d_out;
    float* out_mem = out_x + (size_t)NTOK * E_DIM;

    convert_weights<<<9217, 256, 0, stream>>>(
        (const float4*)w_k, (const float4*)w_q, (const float4*)w_v,
        (const float4*)w_out, (const float4*)w_f1, (const float4*)w_f2,
        b_k, b_q, b_v,
        (uint2*)wkqv, (uint2*)wout, (uint2*)wf1, (uint2*)wf2, bkqv);

    ln1_gates<<<NTOK, 256, 0, stream>>>(x, ln1g, ln1b, w_gw, b_gw, w_gf, b_gf, xn, beta, decay);

    // k/q/v: split-K(2) full density (B fits L2 -> no tile swizzle needed)
    gemm_bt<EPI_SPART, 128, 0, 0, 0><<<dim3(6, 64, 2), 256, 0, stream>>>(
        xn, 1024, wkqv, 1024, nullptr, nullptr, kqv, nullptr, 768, 512, kqvPB);
    kqv_act<<<NTOK, 256, 0, stream>>>(kqv, kqvPB, bkqv);

    chunk_prep<<<NCB, 64, 0, stream>>>(beta, decay, P, ww);
    t_kernel<<<dim3(16, NCB), 256, 0, stream>>>(kqv, P, ww, T);
    mem_scan<<<1024, 256, 0, stream>>>(mem0, T, P, states, out_mem);
    qk_attn<<<NCB, 256, 0, stream>>>(kqv, P, ww, Abuf);
    readout_k<<<dim3(4, NCB), 256, 0, stream>>>(kqv, Abuf, states, P, ro);

    gemm_bt<EPI_RESID, 64, 0, 0, 0><<<dim3(8, 128), 256, 0, stream>>>(
        ro, 256, wout, 256, b_out, x, y1, nullptr, 1024, 256, nullptr);

    ln2_kernel<<<NTOK, 256, 0, stream>>>(y1, ln2g, ln2b, h);
    // FFN1: 256^2 certify-ahead pipeline; XCD bands MY=4, 4x4 sub-squares
    gemm8<EPI_GELU, 4, 4, 4><<<dim3(16, 32), 512, 0, stream>>>(
        h, 1024, wf1, 1024, b_f1, nullptr, nullptr, g, 4096, 1024, nullptr);
    // FFN2: 256^2 certify-ahead pipeline + split-K(2); 256 blocks = 1/CU
    gemm8<EPI_SRESID, 4, 4, 4><<<dim3(4, 32, 2), 512, 0, stream>>>(
        g, 4096, wf2, 4096, b_f2, y1, out_x, nullptr, 1024, 2048, p2);
    combine_k<<<8192, 256, 0, stream>>>((float4*)out_x, (const float4*)p2);
}

// Round 4
// 484.840 us; speedup vs baseline: 1.0920x; 1.0744x over previous
//
#include <hip/hip_runtime.h>
#include <stdint.h>

// ---------------- problem constants ----------------
#define E_DIM 1024
#define M_DIM 256
#define B_DIM 4
#define S_DIM 2048
#define NTOK  8192      // B*S
#define CHUNK 64
#define NCHUNK 32       // S / CHUNK
#define NCB   128       // B * NCHUNK

typedef unsigned short u16;
typedef unsigned int   u32;
typedef __attribute__((ext_vector_type(8))) short short8;
typedef __attribute__((ext_vector_type(4))) float floatx4;

// ---------------- workspace layout (bytes) ----------------
#define OFF_WKQV   ((size_t)0)            // 768*1024 bf16 = 1,572,864
#define OFF_WOUT   ((size_t)1572864)      // 1024*256 bf16 = 524,288
#define OFF_WF1    ((size_t)2097152)      // 4096*1024 bf16 = 8,388,608
#define OFF_WF2    ((size_t)10485760)     // 8,388,608
#define OFF_BKQV   ((size_t)18874368)     // 768 f32
#define OFF_BETA   ((size_t)18877440)     // 8192 f32
#define OFF_DECAY  ((size_t)18910208)     // 8192 f32
#define OFF_P      ((size_t)18942976)     // 128*65 f32
#define OFF_WW     ((size_t)18976256)     // 128*64 f32
#define OFF_ABUF   ((size_t)19009024)     // 128*64*64 f32 = 2,097,152
#define OFF_XN     ((size_t)21106176)     // 8192*1024 bf16 = 16,777,216  [h, ffn2-partial alias]
#define OFF_KQV    ((size_t)37883392)     // 8192*768 f32 = 25,165,824    [kqv split-K partial A]
#define OFF_T      ((size_t)63049216)     // 128*65536 f32 = 33,554,432   [kqv partial B, then T, then y1]
#define OFF_STATES ((size_t)96603648)     // 128*65536 f32 = 33,554,432   [g starts here]
#define OFF_RO     ((size_t)130158080)    // 8192*256 bf16 = 4,194,304
#define OFF_H      OFF_XN                 // 8192*1024 bf16 (xn dead after kqv gemm)
#define OFF_Y1     OFF_T                  // 8192*1024 f32 (T dead after mem_scan)
#define OFF_G      OFF_STATES             // 8192*4096 bf16 = 67,108,864 (states+ro dead)
#define OFF_P2     OFF_XN                 // 8192*1024 f32 FFN2 split-K partial (h/kqv dead)

// ---------------- helpers ----------------
__device__ __forceinline__ u16 f2bf(float f) {
    union { float f; u32 u; } a; a.f = f;
    u32 u = a.u;
    return (u16)((u + 0x7fffu + ((u >> 16) & 1u)) >> 16);
}
__device__ __forceinline__ u32 pack2bf(float a, float b) {
    return (u32)f2bf(a) | ((u32)f2bf(b) << 16);
}
__device__ __forceinline__ float sigmoidf_(float x) { return 1.0f / (1.0f + expf(-x)); }

// fast GELU (erf via Abramowitz-Stegun 7.1.26, |eps| <= 1.5e-7; branchless).
// Replaces libm erff (~30-40 VALU incl. dual-path) with ~14 VALU. Epilogue at
// 1-2 blocks/CU was serialized VALU (R8 audit: 128 erff/thread).
__device__ __forceinline__ float gelu_fast(float v) {
    float z = __builtin_fabsf(v) * 0.70710678118654752f;
    float t = __builtin_amdgcn_rcpf(1.0f + 0.3275911f * z);
    float p = t * (0.254829592f + t * (-0.284496736f +
              t * (1.421413741f + t * (-1.453152027f + t * 1.061405429f))));
    float e = __expf(-z * z);
    float erfz = 1.0f - p * e;
    float s = (v < 0.0f) ? -erfz : erfz;
    return 0.5f * v * (1.0f + s);
}

// async global->LDS, 16 bytes per lane; LDS dest contiguous in lane order.
__device__ __forceinline__ void gload_lds16(const u16* g, u16* l) {
    __builtin_amdgcn_global_load_lds((const __attribute__((address_space(1))) void*)g,
                                     (__attribute__((address_space(3))) void*)l, 16, 0, 0);
}

// XOR-swizzle for a [rows][32] u16 region (verified: SQ_LDS_BANK_CONFLICT -> 0)
__device__ __forceinline__ int sw_slot(int idx) {
    return ((idx & 3) ^ ((idx >> 3) & 3)) * 8;
}
__device__ __forceinline__ int sw_read(int row, int kc) {
    return row * 32 + ((kc ^ ((row >> 1) & 3)) << 3);
}

// two-value block reduction across 256 threads (4 waves)
__device__ __forceinline__ void block_reduce_2(float& a, float& b, float* red, int t) {
#pragma unroll
    for (int o = 32; o > 0; o >>= 1) { a += __shfl_xor(a, o); b += __shfl_xor(b, o); }
    if ((t & 63) == 0) { red[t >> 6] = a; red[4 + (t >> 6)] = b; }
    __syncthreads();
    a = red[0] + red[1] + red[2] + red[3];
    b = red[4] + red[5] + red[6] + red[7];
    __syncthreads();
}

// ---------------- unified weight conversion ----------------
__device__ __forceinline__ uint2 cvt4(float4 v) {
    uint2 o; o.x = pack2bf(v.x, v.y); o.y = pack2bf(v.z, v.w); return o;
}
__global__ void convert_weights(const float4* __restrict__ wk, const float4* __restrict__ wq,
                                const float4* __restrict__ wv, const float4* __restrict__ wo,
                                const float4* __restrict__ wf1in, const float4* __restrict__ wf2in,
                                const float* __restrict__ bk, const float* __restrict__ bq,
                                const float* __restrict__ bv,
                                uint2* __restrict__ wkqv, uint2* __restrict__ wout,
                                uint2* __restrict__ wf1, uint2* __restrict__ wf2,
                                float* __restrict__ bkqv) {
    int b = blockIdx.x, t = threadIdx.x;
    if (b < 768) {
        int i = b * 256 + t;
        int sec = i >> 16, off = i & 65535;
        const float4* s = (sec == 0) ? wk : ((sec == 1) ? wq : wv);
        wkqv[i] = cvt4(s[off]);
    } else if (b < 1024) {
        int i = (b - 768) * 256 + t;
        wout[i] = cvt4(wo[i]);
    } else if (b < 5120) {
        int i = (b - 1024) * 256 + t;
        wf1[i] = cvt4(wf1in[i]);
    } else if (b < 9216) {
        int i = (b - 5120) * 256 + t;
        wf2[i] = cvt4(wf2in[i]);
    } else {
        bkqv[t] = bk[t]; bkqv[256 + t] = bq[t]; bkqv[512 + t] = bv[t];
    }
}

// ---------------- LN kernels ----------------
__global__ __launch_bounds__(256) void ln1_gates(
    const float* __restrict__ x, const float* __restrict__ g, const float* __restrict__ b,
    const float* __restrict__ wgw, const float* __restrict__ bgw,
    const float* __restrict__ wgf, const float* __restrict__ bgf,
    u16* __restrict__ xn, float* __restrict__ beta, float* __restrict__ decay)
{
    __shared__ float red[8];
    const int row = blockIdx.x;
    const int t = threadIdx.x;
    const float4 v = ((const float4*)(x + (size_t)row * E_DIM))[t];
    float s  = v.x + v.y + v.z + v.w;
    float ss = v.x * v.x + v.y * v.y + v.z * v.z + v.w * v.w;
    block_reduce_2(s, ss, red, t);
    const float mean = s * (1.0f / E_DIM);
    const float var  = ss * (1.0f / E_DIM) - mean * mean;
    const float rstd = rsqrtf(var + 1e-5f);
    const float4 gg = ((const float4*)g)[t];
    const float4 bb = ((const float4*)b)[t];
    float4 xnv;
    xnv.x = (v.x - mean) * rstd * gg.x + bb.x;
    xnv.y = (v.y - mean) * rstd * gg.y + bb.y;
    xnv.z = (v.z - mean) * rstd * gg.z + bb.z;
    xnv.w = (v.w - mean) * rstd * gg.w + bb.w;
    uint2 o; o.x = pack2bf(xnv.x, xnv.y); o.y = pack2bf(xnv.z, xnv.w);
    ((uint2*)(xn + (size_t)row * E_DIM))[t] = o;
    const float4 w1 = ((const float4*)wgw)[t];
    const float4 w2 = ((const float4*)wgf)[t];
    float dg = xnv.x * w1.x + xnv.y * w1.y + xnv.z * w1.z + xnv.w * w1.w;
    float df = xnv.x * w2.x + xnv.y * w2.y + xnv.z * w2.z + xnv.w * w2.w;
    block_reduce_2(dg, df, red, t);
    if (t == 0) {
        beta[row]  = sigmoidf_(dg + bgw[0]);
        decay[row] = sigmoidf_(df + bgf[0]);
    }
}

__global__ __launch_bounds__(256) void ln2_kernel(
    const float* __restrict__ y1, const float* __restrict__ g, const float* __restrict__ b,
    u16* __restrict__ h)
{
    __shared__ float red[8];
    const int row = blockIdx.x;
    const int t = threadIdx.x;
    const float4 v = ((const float4*)(y1 + (size_t)row * E_DIM))[t];
    float s  = v.x + v.y + v.z + v.w;
    float ss = v.x * v.x + v.y * v.y + v.z * v.z + v.w * v.w;
    block_reduce_2(s, ss, red, t);
    const float mean = s * (1.0f / E_DIM);
    const float var  = ss * (1.0f / E_DIM) - mean * mean;
    const float rstd = rsqrtf(var + 1e-5f);
    const float4 gg = ((const float4*)g)[t];
    const float4 bb = ((const float4*)b)[t];
    float4 xnv;
    xnv.x = (v.x - mean) * rstd * gg.x + bb.x;
    xnv.y = (v.y - mean) * rstd * gg.y + bb.y;
    xnv.z = (v.z - mean) * rstd * gg.z + bb.z;
    xnv.w = (v.w - mean) * rstd * gg.w + bb.w;
    uint2 o; o.x = pack2bf(xnv.x, xnv.y); o.y = pack2bf(xnv.z, xnv.w);
    ((uint2*)(h + (size_t)row * E_DIM))[t] = o;
}

// ---------------- k/q/v: combine split-K partials + bias, then activations ----------------
__global__ __launch_bounds__(256) void kqv_act(float* __restrict__ pA,
                                               const float* __restrict__ pB,
                                               const float* __restrict__ bias) {
    __shared__ float red[8];
    const int row = blockIdx.x;
    const int t = threadIdx.x;
    float* p = pA + (size_t)row * 768;
    const float* q = pB + (size_t)row * 768;
    float kv = p[t]       + q[t]       + bias[t];
    float qv = p[256 + t] + q[256 + t] + bias[256 + t];
    float vv = p[512 + t] + q[512 + t] + bias[512 + t];
    float sk = kv * kv, sq = qv * qv;
    block_reduce_2(sk, sq, red, t);
    float nk = fmaxf(sqrtf(sk), 1e-12f);
    float nq = fmaxf(sqrtf(sq), 1e-12f);
    p[t]       = kv / nk;
    p[256 + t] = qv / nq;
    p[512 + t] = tanhf(vv);
}

// ---------------- chunk prep ----------------
__global__ void chunk_prep(const float* __restrict__ beta, const float* __restrict__ decay,
                           float* __restrict__ P, float* __restrict__ ww) {
    int cb = blockIdx.x;
    int b = cb >> 5, c = cb & 31;
    int tb = b * S_DIM + c * CHUNK;
    int j = threadIdx.x;
    __shared__ float d[64], bt[64], Ps[65];
    d[j]  = decay[tb + j];
    bt[j] = beta[tb + j];
    __syncthreads();
    if (j == 0) {
        float p = 1.0f; Ps[0] = 1.0f;
        for (int i = 0; i < 64; i++) { p *= d[i]; Ps[i + 1] = p; }
    }
    __syncthreads();
    P[cb * 65 + j] = Ps[j];
    if (j == 0) P[cb * 65 + 64] = Ps[64];
    ww[cb * 64 + j] = bt[j] / Ps[j + 1];
}

// ---------------- per-chunk state increment ----------------
__global__ __launch_bounds__(256) void t_kernel(const float* __restrict__ kqv,
                                                const float* __restrict__ P,
                                                const float* __restrict__ ww,
                                                float* __restrict__ T) {
    int cb = blockIdx.y;
    int tile = blockIdx.x;
    int r0 = (tile >> 2) * 64, c0 = (tile & 3) * 64;
    int b = cb >> 5, c = cb & 31;
    int tb = b * S_DIM + c * CHUNK;
    float p64 = P[cb * 65 + 64];
    __shared__ float Vs[64][65], Ks[64][65];
    int t = threadIdx.x;
#pragma unroll
    for (int i = 0; i < 16; i++) {
        int idx = t + i * 256; int j = idx >> 6, col = idx & 63;
        float sc = ww[cb * 64 + j] * p64;
        Vs[j][col] = kqv[(size_t)(tb + j) * 768 + 512 + r0 + col] * sc;
        Ks[j][col] = kqv[(size_t)(tb + j) * 768 + 0   + c0 + col];
    }
    __syncthreads();
    int tr = t >> 4, tc = t & 15;
    float a[4][4] = {};
    for (int j = 0; j < 64; j++) {
        float vv[4], kk[4];
#pragma unroll
        for (int r = 0; r < 4; r++)  vv[r] = Vs[j][tr * 4 + r];
#pragma unroll
        for (int cc = 0; cc < 4; cc++) kk[cc] = Ks[j][tc * 4 + cc];
#pragma unroll
        for (int r = 0; r < 4; r++)
#pragma unroll
            for (int cc = 0; cc < 4; cc++) a[r][cc] += vv[r] * kk[cc];
    }
#pragma unroll
    for (int r = 0; r < 4; r++)
#pragma unroll
        for (int cc = 0; cc < 4; cc++)
            T[(size_t)cb * 65536 + (size_t)(r0 + tr * 4 + r) * 256 + (c0 + tc * 4 + cc)] = a[r][cc];
}

// ---------------- element-parallel chunk scan ----------------
__global__ void mem_scan(const float* __restrict__ mem0, const float* __restrict__ T,
                         const float* __restrict__ P, float* __restrict__ states,
                         float* __restrict__ memOut) {
    int gid = blockIdx.x * 256 + threadIdx.x;
    int b = gid >> 16; int e = gid & 65535;
    float s = mem0[gid];
    for (int c = 0; c < NCHUNK; c++) {
        int cb = b * NCHUNK + c;
        states[(size_t)cb * 65536 + e] = s;
        s = P[cb * 65 + 64] * s + T[(size_t)cb * 65536 + e];
    }
    memOut[gid] = s;
}

// ---------------- intra-chunk attention matrix ----------------
__global__ __launch_bounds__(256) void qk_attn(const float* __restrict__ kqv,
                                               const float* __restrict__ P,
                                               const float* __restrict__ ww,
                                               float* __restrict__ Abuf) {
    int cb = blockIdx.x;
    int b = cb >> 5, c = cb & 31;
    int tb = b * S_DIM + c * CHUNK;
    __shared__ float Qs[64][65], Ks[64][65];
    int t = threadIdx.x;
    int tr = t >> 4, tc = t & 15;
    float acc[4][4] = {};
    for (int kt = 0; kt < 4; kt++) {
        __syncthreads();
#pragma unroll
        for (int i = 0; i < 16; i++) {
            int idx = t + i * 256; int rr = idx >> 6, cc2 = idx & 63;
            Qs[rr][cc2] = kqv[(size_t)(tb + rr) * 768 + 256 + kt * 64 + cc2];
            Ks[rr][cc2] = kqv[(size_t)(tb + rr) * 768 + 0   + kt * 64 + cc2];
        }
        __syncthreads();
        for (int kk = 0; kk < 64; kk++) {
            float qq[4], kx[4];
#pragma unroll
            for (int r = 0; r < 4; r++)  qq[r] = Qs[tr * 4 + r][kk];
#pragma unroll
            for (int cc = 0; cc < 4; cc++) kx[cc] = Ks[tc * 4 + cc][kk];
#pragma unroll
            for (int r = 0; r < 4; r++)
#pragma unroll
                for (int cc = 0; cc < 4; cc++) acc[r][cc] += qq[r] * kx[cc];
        }
    }
#pragma unroll
    for (int r = 0; r < 4; r++) {
#pragma unroll
        for (int cc = 0; cc < 4; cc++) {
            int i = tr * 4 + r, j = tc * 4 + cc;
            float v = (j < i) ? acc[r][cc] * (P[cb * 65 + i] * ww[cb * 64 + j]) : 0.0f;
            Abuf[(size_t)cb * 4096 + i * 64 + j] = v;
        }
    }
}

// ---------------- readout ----------------
__global__ __launch_bounds__(256) void readout_k(const float* __restrict__ kqv,
                                                 const float* __restrict__ Abuf,
                                                 const float* __restrict__ states,
                                                 const float* __restrict__ P,
                                                 u16* __restrict__ ro) {
    int cb = blockIdx.y;
    int rt = blockIdx.x;
    int b = cb >> 5, c = cb & 31;
    int tb = b * S_DIM + c * CHUNK;
    int r0 = rt * 64;
    __shared__ float As[64][65], Vs[64][65], Qs[64][65], Ms[64][65];
    int t = threadIdx.x;
    int tr = t >> 4, tc = t & 15;
#pragma unroll
    for (int i = 0; i < 16; i++) {
        int idx = t + i * 256; int rr = idx >> 6, cc2 = idx & 63;
        As[rr][cc2] = Abuf[(size_t)cb * 4096 + rr * 64 + cc2];
        Vs[rr][cc2] = kqv[(size_t)(tb + rr) * 768 + 512 + r0 + cc2];
    }
    __syncthreads();
    float acc[4][4] = {};
    for (int j = 0; j < 64; j++) {
        float aa[4], vv[4];
#pragma unroll
        for (int r = 0; r < 4; r++)  aa[r] = As[tr * 4 + r][j];
#pragma unroll
        for (int cc = 0; cc < 4; cc++) vv[cc] = Vs[j][tc * 4 + cc];
#pragma unroll
        for (int r = 0; r < 4; r++)
#pragma unroll
            for (int cc = 0; cc < 4; cc++) acc[r][cc] += aa[r] * vv[cc];
    }
    float acc2[4][4] = {};
    for (int kt = 0; kt < 4; kt++) {
        __syncthreads();
#pragma unroll
        for (int i = 0; i < 16; i++) {
            int idx = t + i * 256; int rr = idx >> 6, cc2 = idx & 63;
            Qs[rr][cc2] = kqv[(size_t)(tb + rr) * 768 + 256 + kt * 64 + cc2];
            Ms[rr][cc2] = states[(size_t)cb * 65536 + (size_t)(r0 + rr) * 256 + kt * 64 + cc2];
        }
        __syncthreads();
        for (int kk = 0; kk < 64; kk++) {
            float qq[4], mm[4];
#pragma unroll
            for (int r = 0; r < 4; r++)  qq[r] = Qs[tr * 4 + r][kk];
#pragma unroll
            for (int cc = 0; cc < 4; cc++) mm[cc] = Ms[tc * 4 + cc][kk];
#pragma unroll
            for (int r = 0; r < 4; r++)
#pragma unroll
                for (int cc = 0; cc < 4; cc++) acc2[r][cc] += qq[r] * mm[cc];
        }
    }
#pragma unroll
    for (int r = 0; r < 4; r++) {
#pragma unroll
        for (int cc = 0; cc < 4; cc++) {
            int i = tr * 4 + r;
            float val = acc[r][cc] + P[cb * 65 + i] * acc2[r][cc];
            ro[(size_t)(tb + i) * 256 + r0 + tc * 4 + cc] = f2bf(val);
        }
    }
}

// ---------------- split-K combine: out += partial ----------------
__global__ __launch_bounds__(256) void combine_k(float4* __restrict__ out,
                                                 const float4* __restrict__ part) {
    int i = blockIdx.x * 256 + threadIdx.x;
    float4 a = out[i], b = part[i];
    a.x += b.x; a.y += b.y; a.z += b.z; a.w += b.w;
    out[i] = a;
}

#define EPI_BIAS   0
#define EPI_RESID  1
#define EPI_GELU   2
#define EPI_SPART  3
#define EPI_SRESID 4

// ---------------- bf16 MFMA GEMM: 128-tile (kqv / wout) ----------------
// R0-proven 2-buffer structure (R1's 3-buf cost occupancy on these short-K shapes).
template<int EPI, int BM, int MY, int SQH, int SQW>
__global__ __launch_bounds__(256) void gemm_bt(
    const u16* __restrict__ A, int lda,
    const u16* __restrict__ B, int ldb,
    const float* __restrict__ bias,
    const float* __restrict__ resid,
    float* __restrict__ outF, u16* __restrict__ outB,
    int ldc, int K, float* __restrict__ part)
{
    constexpr int MI = BM / 32;
    __shared__ u16 As[2][BM * 32];
    __shared__ u16 Bs[2][128 * 32];
    const int t = threadIdx.x;
    const int lane = t & 63;
    const int w = t >> 6;
    const int waveM = (w >> 1) * (BM / 2);
    const int waveN = (w & 1) * 64;

    int bx, by;
    if (MY == 0) {
        bx = blockIdx.x; by = blockIdx.y;
    } else {
        const u32 NX = gridDim.x;
        u32 flat = blockIdx.x + NX * blockIdx.y;
        u32 xcd = flat & 7;
        u32 local = flat >> 3;
        u32 perBand = (u32)SQH * NX;
        u32 band = local / perBand;
        u32 rem  = local - band * perBand;
        u32 sq   = rem / (SQH * SQW);
        u32 wloc = rem - sq * (SQH * SQW);
        u32 wy = wloc / SQW, wx = wloc - wy * SQW;
        by = xcd * MY + band * SQH + wy;
        bx = sq * SQW + wx;
    }

    const int m0 = by * BM;
    const int n0 = bx * 128;
    const size_t koff = (size_t)blockIdx.z * K;

    const int sr = t >> 2, scw = sw_slot(t);
    const u16* Ag0 = A + (size_t)(m0 + sr) * lda + koff + scw;
    const u16* Ag1 = A + (size_t)(m0 + 64 + sr) * lda + koff + scw;   // BM==128 only
    const u16* Bg0 = B + (size_t)(n0 + sr) * ldb + koff + scw;
    const u16* Bg1 = B + (size_t)(n0 + 64 + sr) * ldb + koff + scw;

    floatx4 acc[MI][4] = {};

    const int kc = lane >> 4;
    const int rsel = lane & 15;
    const int NK = K >> 5;

    gload_lds16(Ag0, As[0] + t * 8);
    if (BM == 128) gload_lds16(Ag1, As[0] + (t + 256) * 8);
    gload_lds16(Bg0, Bs[0] + t * 8);
    gload_lds16(Bg1, Bs[0] + (t + 256) * 8);

    for (int kt = 0; kt < NK; kt++) {
        __syncthreads();
        const int cur = kt & 1;
        if (kt + 1 < NK) {
            const int kof = (kt + 1) * 32;
            gload_lds16(Ag0 + kof, As[cur ^ 1] + t * 8);
            if (BM == 128) gload_lds16(Ag1 + kof, As[cur ^ 1] + (t + 256) * 8);
            gload_lds16(Bg0 + kof, Bs[cur ^ 1] + t * 8);
            gload_lds16(Bg1 + kof, Bs[cur ^ 1] + (t + 256) * 8);
        }
        short8 af[MI], bfr[4];
#pragma unroll
        for (int i = 0; i < MI; i++)
            af[i] = *(const short8*)(As[cur] + sw_read(waveM + i * 16 + rsel, kc));
#pragma unroll
        for (int j = 0; j < 4; j++)
            bfr[j] = *(const short8*)(Bs[cur] + sw_read(waveN + j * 16 + rsel, kc));
#pragma unroll
        for (int i = 0; i < MI; i++)
#pragma unroll
            for (int j = 0; j < 4; j++)
                acc[i][j] = __builtin_amdgcn_mfma_f32_16x16x32_bf16(af[i], bfr[j], acc[i][j], 0, 0, 0);
    }

    const bool zmain = (blockIdx.z == 0);
    const int rbase = (lane >> 4) * 4;
#pragma unroll
    for (int i = 0; i < MI; i++) {
#pragma unroll
        for (int j = 0; j < 4; j++) {
            const int col = n0 + waveN + j * 16 + rsel;
            float bv = 0.0f;
            if (EPI == EPI_BIAS || EPI == EPI_RESID || EPI == EPI_GELU) bv = bias[col];
            if (EPI == EPI_SRESID && zmain) bv = bias[col];
#pragma unroll
            for (int r = 0; r < 4; r++) {
                const int row = m0 + waveM + i * 16 + rbase + r;
                const size_t oidx = (size_t)row * ldc + col;
                float v = acc[i][j][r] + bv;
                if (EPI == EPI_BIAS) {
                    outF[oidx] = v;
                } else if (EPI == EPI_RESID) {
                    outF[oidx] = v + resid[oidx];
                } else if (EPI == EPI_GELU) {
                    outB[oidx] = f2bf(gelu_fast(v));
                } else if (EPI == EPI_SPART) {
                    (zmain ? outF : part)[oidx] = v;
                } else { // EPI_SRESID
                    if (zmain) outF[oidx] = v + resid[oidx];
                    else       part[oidx] = v;
                }
            }
        }
    }
}

// ---------------- bf16 MFMA GEMM: 256x128, 3-slot pipeline, 2 blocks/CU (FFN) ----------------
// R9: the R7/R8 256^2 gemm8 ran 1 block/CU (128KB LDS) -> zero co-resident work
// during vmcnt stalls AND during the heavy epilogue (128 erf + 128 2B-stores per
// thread) -> stuck at ~654 TF. This kernel restores TLP: 256(M)x128(N) tile,
// region = 32-k slice of A+B = 24KB, 3 slots = 72KB -> 2 blocks/CU
// (launch_bounds(512,4) caps VGPR at 128; acc[4][4]=64). Counted-vmcnt ledger
// per phase p: frags(p) [certified at p-1] -> STAGE(p+2) [slot last read at
// p-1] -> vmcnt(3) [certify p+1; p+2's 3 loads stay in flight, never drain
// mid-loop] -> s_barrier -> lgkm(0) -> setprio 16xMFMA. Phase = 16 MFMA/wave
// (m201 granularity); cross-block TLP hides load latency and epilogues.
template<int EPI, int MY, int SQH, int SQW>
__global__ __launch_bounds__(512, 4) void gemm_hk(
    const u16* __restrict__ A, int lda,
    const u16* __restrict__ B, int ldb,
    const float* __restrict__ bias,
    const float* __restrict__ resid,
    float* __restrict__ outF, u16* __restrict__ outB,
    int ldc, int K, float* __restrict__ part)
{
    __shared__ u16 L[3][12288];        // slot: A 256x32 (8192 u16) + B 128x32 (4096 u16) = 24KB
    const int t = threadIdx.x;
    const int lane = t & 63;
    const int w = t >> 6;              // 8 waves: 4 M-rows x 2 N-cols
    const int waveM = (w >> 1) * 64;
    const int waveN = (w & 1) * 64;
    const int kc = lane >> 4;
    const int rsel = lane & 15;

    int bx, by;
    {
        const u32 NX = gridDim.x;
        u32 flat = blockIdx.x + NX * blockIdx.y;
        u32 xcd = flat & 7;
        u32 local = flat >> 3;
        u32 perBand = (u32)SQH * NX;
        u32 band = local / perBand;
        u32 rem  = local - band * perBand;
        u32 sq   = rem / (SQH * SQW);
        u32 wloc = rem - sq * (SQH * SQW);
        u32 wy = wloc / SQW, wx = wloc - wy * SQW;
        by = xcd * MY + band * SQH + wy;
        bx = sq * SQW + wx;
    }
    const int m0 = by * 256;
    const int n0 = bx * 128;
    const size_t koff = (size_t)blockIdx.z * K;

    const int srow = t >> 2;           // 512 thr -> 128 rows per gload
    const int scw  = sw_slot(t);
    const u16* Asrc = A + (size_t)(m0 + srow) * lda + koff + scw;
    const u16* Bsrc = B + (size_t)(n0 + srow) * ldb + koff + scw;

    floatx4 acc[4][4] = {};
    const int NR = K >> 5;

    auto STAGE = [&](int r, int slot) {
        const int ko = r * 32;
        u16* la = &L[slot][0];
        u16* lb = &L[slot][8192];
        gload_lds16(Asrc + ko, la + t * 8);
        gload_lds16(Asrc + (size_t)128 * lda + ko, la + 4096 + t * 8);
        gload_lds16(Bsrc + ko, lb + t * 8);
    };

    // prologue: regions 0,1 in flight; certify region 0 (region 1 stays in flight)
    STAGE(0, 0); STAGE(1, 1);
    asm volatile("s_waitcnt vmcnt(3)" ::: "memory");
    __builtin_amdgcn_s_barrier();
    __builtin_amdgcn_sched_barrier(0);

    int sc = 0;                        // slot of region p
    for (int p = 0; p < NR; ++p) {
        // 1) reads of region p (certified at previous phase's vmcnt+barrier)
        short8 af[4], bv[4];
#pragma unroll
        for (int i = 0; i < 4; i++)
            af[i] = *(const short8*)(&L[sc][0] + sw_read(waveM + i * 16 + rsel, kc));
#pragma unroll
        for (int j = 0; j < 4; j++)
            bv[j] = *(const short8*)(&L[sc][8192] + sw_read(waveN + j * 16 + rsel, kc));
        // 2) stage region p+2 into the slot last read at phase p-1
        if (p + 2 < NR) {
            int ss = sc + 2; if (ss >= 3) ss -= 3;
            STAGE(p + 2, ss);
        }
        // 3) certify region p+1 (counted: p+2's loads stay in flight)
        if (p + 1 < NR) {
            if (p + 2 < NR) { asm volatile("s_waitcnt vmcnt(3)" ::: "memory"); }
            else            { asm volatile("s_waitcnt vmcnt(0)" ::: "memory"); }
            __builtin_amdgcn_s_barrier();
            __builtin_amdgcn_sched_barrier(0);
        }
        // 4) own reads complete -> compute
        asm volatile("s_waitcnt lgkmcnt(0)" ::: "memory");
        __builtin_amdgcn_sched_barrier(0);
        __builtin_amdgcn_s_setprio(1);
#pragma unroll
        for (int i = 0; i < 4; i++)
#pragma unroll
            for (int j = 0; j < 4; j++)
                acc[i][j] = __builtin_amdgcn_mfma_f32_16x16x32_bf16(af[i], bv[j], acc[i][j], 0, 0, 0);
        __builtin_amdgcn_s_setprio(0);
        sc = (sc + 1 == 3) ? 0 : sc + 1;
    }

    const bool zmain = (blockIdx.z == 0);
    const int rbase = kc * 4;
#pragma unroll
    for (int i = 0; i < 4; i++) {
#pragma unroll
        for (int j = 0; j < 4; j++) {
            const int col = n0 + waveN + j * 16 + rsel;
            float bvv = 0.0f;
            if (EPI == EPI_BIAS || EPI == EPI_RESID || EPI == EPI_GELU) bvv = bias[col];
            if (EPI == EPI_SRESID && zmain) bvv = bias[col];
#pragma unroll
            for (int r = 0; r < 4; r++) {
                const int row = m0 + waveM + i * 16 + rbase + r;
                const size_t oidx = (size_t)row * ldc + col;
                float v = acc[i][j][r] + bvv;
                if (EPI == EPI_BIAS) {
                    outF[oidx] = v;
                } else if (EPI == EPI_RESID) {
                    outF[oidx] = v + resid[oidx];
                } else if (EPI == EPI_GELU) {
                    outB[oidx] = f2bf(gelu_fast(v));
                } else if (EPI == EPI_SPART) {
                    (zmain ? outF : part)[oidx] = v;
                } else { // EPI_SRESID
                    if (zmain) outF[oidx] = v + resid[oidx];
                    else       part[oidx] = v;
                }
            }
        }
    }
}

// ---------------- launch ----------------
extern "C" void kernel_launch(void* const* d_in, const int* in_sizes, int n_in,
                              void* d_out, int out_size, void* d_ws, size_t ws_size,
                              hipStream_t stream) {
    const float* x     = (const float*)d_in[0];
    const float* mem0  = (const float*)d_in[1];
    const float* w_k   = (const float*)d_in[2];
    const float* b_k   = (const float*)d_in[3];
    const float* w_q   = (const float*)d_in[4];
    const float* b_q   = (const float*)d_in[5];
    const float* w_v   = (const float*)d_in[6];
    const float* b_v   = (const float*)d_in[7];
    const float* w_out = (const float*)d_in[8];
    const float* b_out = (const float*)d_in[9];
    const float* w_gw  = (const float*)d_in[10];
    const float* b_gw  = (const float*)d_in[11];
    const float* w_gf  = (const float*)d_in[12];
    const float* b_gf  = (const float*)d_in[13];
    const float* ln1g  = (const float*)d_in[14];
    const float* ln1b  = (const float*)d_in[15];
    const float* ln2g  = (const float*)d_in[16];
    const float* ln2b  = (const float*)d_in[17];
    const float* w_f1  = (const float*)d_in[18];
    const float* b_f1  = (const float*)d_in[19];
    const float* w_f2  = (const float*)d_in[20];
    const float* b_f2  = (const float*)d_in[21];

    char* ws = (char*)d_ws;
    u16*   wkqv  = (u16*)(ws + OFF_WKQV);
    u16*   wout  = (u16*)(ws + OFF_WOUT);
    u16*   wf1   = (u16*)(ws + OFF_WF1);
    u16*   wf2   = (u16*)(ws + OFF_WF2);
    float* bkqv  = (float*)(ws + OFF_BKQV);
    float* beta  = (float*)(ws + OFF_BETA);
    float* decay = (float*)(ws + OFF_DECAY);
    float* P     = (float*)(ws + OFF_P);
    float* ww    = (float*)(ws + OFF_WW);
    float* Abuf  = (float*)(ws + OFF_ABUF);
    u16*   xn    = (u16*)(ws + OFF_XN);
    float* kqv   = (float*)(ws + OFF_KQV);
    float* kqvPB = (float*)(ws + OFF_T);
    float* T     = (float*)(ws + OFF_T);
    float* states= (float*)(ws + OFF_STATES);
    u16*   ro    = (u16*)(ws + OFF_RO);
    u16*   h     = (u16*)(ws + OFF_H);
    float* y1    = (float*)(ws + OFF_Y1);
    u16*   g     = (u16*)(ws + OFF_G);
    float* p2    = (float*)(ws + OFF_P2);

    float* out_x   = (float*)d_out;
    float* out_mem = out_x + (size_t)NTOK * E_DIM;

    convert_weights<<<9217, 256, 0, stream>>>(
        (const float4*)w_k, (const float4*)w_q, (const float4*)w_v,
        (const float4*)w_out, (const float4*)w_f1, (const float4*)w_f2,
        b_k, b_q, b_v,
        (uint2*)wkqv, (uint2*)wout, (uint2*)wf1, (uint2*)wf2, bkqv);

    ln1_gates<<<NTOK, 256, 0, stream>>>(x, ln1g, ln1b, w_gw, b_gw, w_gf, b_gf, xn, beta, decay);

    // k/q/v: split-K(2) full density (B fits L2 -> no tile swizzle needed)
    gemm_bt<EPI_SPART, 128, 0, 0, 0><<<dim3(6, 64, 2), 256, 0, stream>>>(
        xn, 1024, wkqv, 1024, nullptr, nullptr, kqv, nullptr, 768, 512, kqvPB);
    kqv_act<<<NTOK, 256, 0, stream>>>(kqv, kqvPB, bkqv);

    chunk_prep<<<NCB, 64, 0, stream>>>(beta, decay, P, ww);
    t_kernel<<<dim3(16, NCB), 256, 0, stream>>>(kqv, P, ww, T);
    mem_scan<<<1024, 256, 0, stream>>>(mem0, T, P, states, out_mem);
    qk_attn<<<NCB, 256, 0, stream>>>(kqv, P, ww, Abuf);
    readout_k<<<dim3(4, NCB), 256, 0, stream>>>(kqv, Abuf, states, P, ro);

    gemm_bt<EPI_RESID, 64, 0, 0, 0><<<dim3(8, 128), 256, 0, stream>>>(
        ro, 256, wout, 256, b_out, x, y1, nullptr, 1024, 256, nullptr);

    ln2_kernel<<<NTOK, 256, 0, stream>>>(y1, ln2g, ln2b, h);
    // FFN1: 256x128 pipeline, 1024 blocks @ 2/CU; XCD bands MY=4, 4x8 sub-squares (~4MB/XCD)
    gemm_hk<EPI_GELU, 4, 4, 8><<<dim3(32, 32), 512, 0, stream>>>(
        h, 1024, wf1, 1024, b_f1, nullptr, nullptr, g, 4096, 1024, nullptr);
    // FFN2: 256x128 pipeline + split-K(2), 512 blocks @ 2/CU
    gemm_hk<EPI_SRESID, 4, 4, 8><<<dim3(8, 32, 2), 512, 0, stream>>>(
        g, 4096, wf2, 4096, b_f2, y1, out_x, nullptr, 1024, 2048, p2);
    combine_k<<<8192, 256, 0, stream>>>((float4*)out_x, (const float4*)p2);
}